// Round 4
// baseline (3389.180 us; speedup 1.0000x reference)
//
#include <hip/hip_runtime.h>
#include <hip/hip_bf16.h>

#define DEV __device__ __forceinline__

static constexpr int Bc = 8;
static constexpr int L0 = 8192, L1 = 4096, L2c = 2048;
static constexpr int DM = 128, DI = 256, DSt = 16, DTR = 8, NL = 4, NC = 100;
static constexpr int KC = 9;

DEV float sigmoidf_(float x){ return 1.f/(1.f+__expf(-x)); }
DEV float siluf_(float x){ return x*sigmoidf_(x); }
DEV float softplusf_(float x){ return (x>20.f)? x : log1pf(__expf(x)); }

// ---------------- conv0: x(8,4,8192) -> y0(8,128,4096), stride2 pad4, relu
__global__ void k_conv0(const float* __restrict__ x, const float* __restrict__ w,
                        const float* __restrict__ bias, float* __restrict__ y)
{
    int o = blockIdx.x*256 + threadIdx.x;           // (b*128+co)*4096 + t
    int t  = o & (L1-1);
    int co = (o >> 12) & (DM-1);
    int b  = o >> 19;
    const float* wp = w + co*4*KC;
    float acc = bias[co];
    int base = 2*t - 4;
    #pragma unroll
    for (int ci=0; ci<4; ++ci){
        const float* xp = x + (b*4+ci)*L0;
        #pragma unroll
        for (int k=0;k<KC;++k){
            int tt = base + k;
            if (tt >= 0 && tt < L0) acc = fmaf(wp[ci*KC+k], xp[tt], acc);
        }
    }
    y[o] = fmaxf(acc, 0.f);
}

// ---------------- BN train stats -> scale/shift per channel
__global__ void k_bnstats(const float* __restrict__ y, int Lc,
                          const float* __restrict__ g, const float* __restrict__ bta,
                          float* __restrict__ scale, float* __restrict__ shift)
{
    int c = blockIdx.x;
    float s=0.f, sq=0.f;
    int Ntot = Bc*Lc;
    for (int idx=threadIdx.x; idx<Ntot; idx+=256){
        int b = idx / Lc, t = idx - b*Lc;
        float v = y[(b*DM+c)*Lc + t];
        s += v; sq = fmaf(v, v, sq);
    }
    #pragma unroll
    for (int off=32; off; off>>=1){ s += __shfl_down(s, off); sq += __shfl_down(sq, off); }
    __shared__ float rs[4], rq[4];
    int wid = threadIdx.x>>6, lane = threadIdx.x&63;
    if (lane==0){ rs[wid]=s; rq[wid]=sq; }
    __syncthreads();
    if (threadIdx.x==0){
        float S=rs[0]+rs[1]+rs[2]+rs[3];
        float Q=rq[0]+rq[1]+rq[2]+rq[3];
        float inv = 1.f/(float)Ntot;
        float mu = S*inv;
        float var = Q*inv - mu*mu;
        float sc = g[c]*rsqrtf(var + 1e-5f);
        scale[c]=sc; shift[c]=bta[c]-mu*sc;
    }
}

// ---------------- conv1: y0(8,128,4096) [BN applied on read] -> y1(8,128,2048), stride2 pad4, relu
__global__ __launch_bounds__(256) void k_conv1(
    const float* __restrict__ y0, const float* __restrict__ w,
    const float* __restrict__ bias,
    const float* __restrict__ sc0, const float* __restrict__ sh0,
    float* __restrict__ y1)
{
    __shared__ __align__(16) float in_s[DM][76];
    int b  = blockIdx.y;
    int t0 = blockIdx.x * 32;
    for (int idx=threadIdx.x; idx < DM*71; idx += 256){
        int ci = idx / 71, j = idx - ci*71;
        int tt = 2*t0 - 4 + j;
        float v = 0.f;
        if (tt >= 0 && tt < L1) v = fmaf(y0[(b*DM+ci)*L1 + tt], sc0[ci], sh0[ci]);
        in_s[ci][j] = v;
    }
    __syncthreads();
    int co = threadIdx.x & 127;
    int th = threadIdx.x >> 7;       // t-half: 0/1
    float acc[16];
    #pragma unroll
    for (int j=0;j<16;++j) acc[j]=bias[co];
    const float* wp = w + co*DM*KC;
    const int jbase = th*16;
    for (int ci=0; ci<DM; ++ci){
        float wv[KC];
        #pragma unroll
        for (int k=0;k<KC;++k) wv[k] = wp[ci*KC+k];
        const float4* rowp = reinterpret_cast<const float4*>(&in_s[ci][2*jbase]);
        float win[44];
        #pragma unroll
        for (int q=0;q<11;++q){
            float4 v4 = rowp[q];
            win[4*q]=v4.x; win[4*q+1]=v4.y; win[4*q+2]=v4.z; win[4*q+3]=v4.w;
        }
        #pragma unroll
        for (int j=0;j<16;++j)
            #pragma unroll
            for (int k=0;k<KC;++k)
                acc[j] = fmaf(wv[k], win[2*j+k], acc[j]);
    }
    #pragma unroll
    for (int j=0;j<16;++j){
        int t = t0 + jbase + j;
        y1[(b*DM+co)*L2c + t] = fmaxf(acc[j], 0.f);
    }
}

// ---------------- BN apply + transpose: y1(8,128,2048) -> h(8,2048,128)
__global__ void k_bnt(const float* __restrict__ y1, const float* __restrict__ sc,
                      const float* __restrict__ sh, float* __restrict__ h)
{
    __shared__ float tile[32][33];
    int b  = blockIdx.z;
    int c0 = blockIdx.x * 32;
    int t0 = blockIdx.y * 32;
    int tx = threadIdx.x & 31, ty = threadIdx.x >> 5;   // 8 rows
    for (int i=ty; i<32; i+=8)
        tile[i][tx] = fmaf(y1[(b*DM + c0+i)*L2c + t0+tx], sc[c0+i], sh[c0+i]);
    __syncthreads();
    for (int i=ty; i<32; i+=8)
        h[(b*L2c + t0+i)*DM + c0+tx] = tile[tx][i];
}

// ---------------- LayerNorm over D=128, one wave per token
__global__ void k_ln(const float* __restrict__ h, const float* __restrict__ g,
                     const float* __restrict__ bta, float* __restrict__ out)
{
    int tok  = blockIdx.x*4 + (threadIdx.x>>6);
    int lane = threadIdx.x & 63;
    const float2 v = reinterpret_cast<const float2*>(h + tok*DM)[lane];
    float s = v.x + v.y;
    #pragma unroll
    for (int off=32; off; off>>=1) s += __shfl_xor(s, off);
    float mu = s * (1.f/DM);
    float dx = v.x-mu, dy = v.y-mu;
    float q = dx*dx + dy*dy;
    #pragma unroll
    for (int off=32; off; off>>=1) q += __shfl_xor(q, off);
    float rstd = rsqrtf(q*(1.f/DM) + 1e-5f);
    float2 gg = reinterpret_cast<const float2*>(g)[lane];
    float2 bb = reinterpret_cast<const float2*>(bta)[lane];
    float2 o;
    o.x = fmaf(dx*rstd, gg.x, bb.x);
    o.y = fmaf(dy*rstd, gg.y, bb.y);
    reinterpret_cast<float2*>(out + tok*DM)[lane] = o;
}

// ---------------- generic fp32 GEMM: C[M,N] (+)= A[M,K] @ W[N,K]^T (+bias)(+act)
// BM=BN=64, BK=16, 256 threads, 4x4 microtile
template<int ACT, bool ACC, bool HASB>
__global__ __launch_bounds__(256) void k_gemm(
    const float* __restrict__ A, int lda,
    const float* __restrict__ W, int ldw,
    const float* __restrict__ bias,
    float* __restrict__ C, int ldc,
    int M, int N, int K)
{
    __shared__ __align__(16) float As[16][68];
    __shared__ __align__(16) float Ws[16][68];
    int m0 = blockIdx.x*64, n0 = blockIdx.y*64;
    int tx = threadIdx.x & 15, ty = threadIdx.x >> 4;
    float acc[4][4] = {};
    for (int k0 = 0; k0 < K; k0 += 16){
        __syncthreads();
        {
            int r = threadIdx.x >> 2;
            int cbase = (threadIdx.x & 3) * 4;
            const float* ap = A + (m0+r)*lda + k0;
            #pragma unroll
            for (int q=0;q<4;++q){
                int col = cbase+q;
                As[col][r] = (k0+col < K) ? ap[col] : 0.f;
            }
            const float* wp2 = W + (n0+r)*ldw + k0;
            bool nok = (n0 + r) < N;
            #pragma unroll
            for (int q=0;q<4;++q){
                int col = cbase+q;
                Ws[col][r] = (nok && (k0+col < K)) ? wp2[col] : 0.f;
            }
        }
        __syncthreads();
        #pragma unroll
        for (int kk=0; kk<16; ++kk){
            float4 a4 = *reinterpret_cast<const float4*>(&As[kk][ty*4]);
            float4 w4 = *reinterpret_cast<const float4*>(&Ws[kk][tx*4]);
            float av[4] = {a4.x,a4.y,a4.z,a4.w};
            float wv[4] = {w4.x,w4.y,w4.z,w4.w};
            #pragma unroll
            for (int i=0;i<4;++i)
                #pragma unroll
                for (int j=0;j<4;++j)
                    acc[i][j] = fmaf(av[i], wv[j], acc[i][j]);
        }
    }
    #pragma unroll
    for (int i=0;i<4;++i){
        int m = m0 + ty*4 + i;
        #pragma unroll
        for (int j=0;j<4;++j){
            int n = n0 + tx*4 + j;
            if (n < N){
                float v = acc[i][j];
                if (HASB) v += bias[n];
                if (ACT==1) v = softplusf_(v);
                float* cp = C + m*ldc + n;
                if (ACC) *cp += v; else *cp = v;
            }
        }
    }
}

// ---------------- depthwise causal conv (k=4) + bias + silu, from xz[:, :, :256]
__global__ void k_dwconv(const float* __restrict__ xz, const float* __restrict__ w,
                         const float* __restrict__ bias, float* __restrict__ xmc)
{
    int o = blockIdx.x*256 + threadIdx.x;   // (b*2048+t)*256 + d
    int d = o & 255, t = (o>>8) & 2047, b = o >> 19;
    float acc = bias[d];
    #pragma unroll
    for (int k=0;k<4;++k){
        int tt = t - 3 + k;
        if (tt >= 0) acc = fmaf(w[d*4+k], xz[(b*L2c+tt)*512 + d], acc);
    }
    xmc[o] = siluf_(acc);
}

// ---------------- selective scan: 16 lanes per (b,d), lane = state index
__global__ __launch_bounds__(256) void k_scan(
    const float* __restrict__ dtb, const float* __restrict__ xm,
    const float* __restrict__ xdbl, const float* __restrict__ xz,
    const float* __restrict__ A_log, const float* __restrict__ Dp,
    float* __restrict__ yb)
{
    int g = threadIdx.x >> 4, n = threadIdx.x & 15;
    int idx = blockIdx.x*16 + g;
    int b = idx >> 8, d = idx & 255;
    float An = -__expf(A_log[d*DSt + n]);
    float Dv = Dp[d];
    const float* dtp = dtb + b*L2c*DI + d;
    const float* up  = xm  + b*L2c*DI + d;
    const float* zp  = xz  + b*L2c*2*DI + DI + d;
    const float* Bp  = xdbl + b*L2c*40 + DTR + n;
    const float* Cp  = Bp + DSt;
    float* yp = yb + b*L2c*DI + d;
    float hst = 0.f;
    constexpr int UN = 8;
    float ldt[UN], lu[UN], lz[UN], lB[UN], lC[UN];
    #pragma unroll
    for (int j=0;j<UN;++j){
        ldt[j]=dtp[j*DI]; lu[j]=up[j*DI]; lz[j]=zp[j*2*DI];
        lB[j]=Bp[j*40]; lC[j]=Cp[j*40];
    }
    for (int tc=0; tc<L2c; tc+=UN){
        float cdt[UN],cu[UN],cz[UN],cB[UN],cC[UN];
        #pragma unroll
        for (int j=0;j<UN;++j){cdt[j]=ldt[j];cu[j]=lu[j];cz[j]=lz[j];cB[j]=lB[j];cC[j]=lC[j];}
        if (tc+UN < L2c){
            #pragma unroll
            for (int j=0;j<UN;++j){
                int t2 = tc+UN+j;
                ldt[j]=dtp[t2*DI]; lu[j]=up[t2*DI]; lz[j]=zp[t2*2*DI];
                lB[j]=Bp[t2*40]; lC[j]=Cp[t2*40];
            }
        }
        #pragma unroll
        for (int j=0;j<UN;++j){
            float dA  = __expf(cdt[j]*An);
            float dBu = cdt[j]*cu[j]*cB[j];
            hst = fmaf(dA, hst, dBu);
            float p = hst*cC[j];
            p += __shfl_xor(p,1); p += __shfl_xor(p,2);
            p += __shfl_xor(p,4); p += __shfl_xor(p,8);
            if (n == (j & 15)) yp[(tc+j)*DI] = (p + cu[j]*Dv)*siluf_(cz[j]);
        }
    }
}

// ---------------- final pool: mean over t of ln -> pooled(8,128)
__global__ void k_pool(const float* __restrict__ ln, float* __restrict__ pooled)
{
    __shared__ float sbuf[256];
    int b = blockIdx.x;
    int c = threadIdx.x & 127, half = threadIdx.x >> 7;
    float s = 0.f;
    for (int t = half; t < L2c; t += 2) s += ln[(b*L2c+t)*DM + c];
    sbuf[threadIdx.x] = s;
    __syncthreads();
    if (half == 0) pooled[b*DM+c] = (s + sbuf[threadIdx.x+128]) * (1.f/(float)L2c);
}

// ---------------- classifier: pooled(8,128) @ cls_w(100,128)^T + b -> out(8,100)
__global__ void k_cls(const float* __restrict__ pooled, const float* __restrict__ w,
                      const float* __restrict__ bias, float* __restrict__ out)
{
    int o = blockIdx.x*256 + threadIdx.x;
    if (o >= Bc*NC) return;
    int b = o/NC, n = o - b*NC;
    float s = bias[n];
    const float* pp = pooled + b*DM;
    const float* wp = w + n*DM;
    #pragma unroll 4
    for (int k=0;k<DM;++k) s = fmaf(pp[k], wp[k], s);
    out[o] = s;
}

extern "C" void kernel_launch(void* const* d_in, const int* in_sizes, int n_in,
                              void* d_out, int out_size, void* d_ws, size_t ws_size,
                              hipStream_t stream)
{
    const float* x        = (const float*)d_in[0];
    const float* conv0_w  = (const float*)d_in[1];
    const float* conv0_b  = (const float*)d_in[2];
    const float* bn0_g    = (const float*)d_in[3];
    const float* bn0_b    = (const float*)d_in[4];
    const float* conv1_w  = (const float*)d_in[5];
    const float* conv1_b  = (const float*)d_in[6];
    const float* bn1_g    = (const float*)d_in[7];
    const float* bn1_b    = (const float*)d_in[8];
    const float* ln_g     = (const float*)d_in[9];
    const float* ln_b     = (const float*)d_in[10];
    const float* in_proj_w= (const float*)d_in[11];
    const float* mconv_w  = (const float*)d_in[12];
    const float* mconv_b  = (const float*)d_in[13];
    const float* xproj_w  = (const float*)d_in[14];
    const float* dtproj_w = (const float*)d_in[15];
    const float* dtproj_b = (const float*)d_in[16];
    const float* A_log    = (const float*)d_in[17];
    const float* D_skip   = (const float*)d_in[18];
    const float* outproj_w= (const float*)d_in[19];
    const float* fnorm_g  = (const float*)d_in[20];
    const float* fnorm_b  = (const float*)d_in[21];
    const float* cls_w    = (const float*)d_in[22];
    const float* cls_b    = (const float*)d_in[23];
    float* out = (float*)d_out;

    float* ws = (float*)d_ws;
    float* sc0 = ws;        float* sh0 = ws+128;
    float* sc1 = ws+256;    float* sh1 = ws+384;
    float* h    = ws + 1024;              // 2,097,152
    float* ln   = h   + 2097152;          // 2,097,152
    float* xz   = ln  + 2097152;          // 8,388,608   (y0 aliases here)
    float* y0   = xz;
    float* xmc  = xz  + 8388608;          // 4,194,304   (y1 aliases here)
    float* y1   = xmc;
    float* xdbl = xmc + 4194304;          // 655,360
    float* dtb  = xdbl+ 655360;           // 4,194,304
    float* yb   = dtb + 4194304;          // 4,194,304
    float* pooled = yb + 4194304;         // 1,024

    // conv stage
    k_conv0<<<16384, 256, 0, stream>>>(x, conv0_w, conv0_b, y0);
    k_bnstats<<<128, 256, 0, stream>>>(y0, L1, bn0_g, bn0_b, sc0, sh0);
    k_conv1<<<dim3(L2c/32, Bc), 256, 0, stream>>>(y0, conv1_w, conv1_b, sc0, sh0, y1);
    k_bnstats<<<128, 256, 0, stream>>>(y1, L2c, bn1_g, bn1_b, sc1, sh1);
    k_bnt<<<dim3(4, 64, Bc), 256, 0, stream>>>(y1, sc1, sh1, h);

    for (int i=0;i<NL;++i){
        k_ln<<<4096, 256, 0, stream>>>(h, ln_g + i*DM, ln_b + i*DM, ln);
        k_gemm<0,false,false><<<dim3(256, 8), 256, 0, stream>>>(
            ln, DM, in_proj_w + i*512*DM, DM, nullptr, xz, 512, 16384, 512, DM);
        k_dwconv<<<16384, 256, 0, stream>>>(xz, mconv_w + i*DI*4, mconv_b + i*DI, xmc);
        k_gemm<0,false,false><<<dim3(256, 1), 256, 0, stream>>>(
            xmc, DI, xproj_w + i*40*DI, DI, nullptr, xdbl, 40, 16384, 40, DI);
        k_gemm<1,false,true><<<dim3(256, 4), 256, 0, stream>>>(
            xdbl, 40, dtproj_w + i*DI*DTR, DTR, dtproj_b + i*DI, dtb, DI, 16384, DI, DTR);
        k_scan<<<128, 256, 0, stream>>>(dtb, xmc, xdbl, xz,
            A_log + i*DI*DSt, D_skip + i*DI, yb);
        k_gemm<0,true,false><<<dim3(256, 2), 256, 0, stream>>>(
            yb, DI, outproj_w + i*DM*DI, DI, nullptr, h, DM, 16384, DM, DI);
    }

    k_ln<<<4096, 256, 0, stream>>>(h, fnorm_g, fnorm_b, ln);
    k_pool<<<Bc, 256, 0, stream>>>(ln, pooled);
    k_cls<<<4, 256, 0, stream>>>(pooled, cls_w, cls_b, out);
}

// Round 5
// 1909.438 us; speedup vs baseline: 1.7750x; 1.7750x over previous
//
#include <hip/hip_runtime.h>
#include <hip/hip_bf16.h>

#define DEV __device__ __forceinline__

static constexpr int Bc = 8;
static constexpr int L0 = 8192, L1 = 4096, L2c = 2048;
static constexpr int DM = 128, DI = 256, DSt = 16, DTR = 8, NL = 4, NC = 100;
static constexpr int KC = 9;
static constexpr int TC = 128, NCH = 16;   // scan chunking: 16 chunks of 128 steps

DEV float sigmoidf_(float x){ return 1.f/(1.f+__expf(-x)); }
DEV float siluf_(float x){ return x*sigmoidf_(x); }
DEV float softplusf_(float x){ return (x>20.f)? x : log1pf(__expf(x)); }

// ---------------- conv0: x(8,4,8192) -> y0(8,128,4096), stride2 pad4, relu
__global__ void k_conv0(const float* __restrict__ x, const float* __restrict__ w,
                        const float* __restrict__ bias, float* __restrict__ y)
{
    int o = blockIdx.x*256 + threadIdx.x;           // (b*128+co)*4096 + t
    int t  = o & (L1-1);
    int co = (o >> 12) & (DM-1);
    int b  = o >> 19;
    const float* wp = w + co*4*KC;
    float acc = bias[co];
    int base = 2*t - 4;
    #pragma unroll
    for (int ci=0; ci<4; ++ci){
        const float* xp = x + (b*4+ci)*L0;
        #pragma unroll
        for (int k=0;k<KC;++k){
            int tt = base + k;
            if (tt >= 0 && tt < L0) acc = fmaf(wp[ci*KC+k], xp[tt], acc);
        }
    }
    y[o] = fmaxf(acc, 0.f);
}

// ---------------- BN train stats -> scale/shift per channel
__global__ void k_bnstats(const float* __restrict__ y, int Lc,
                          const float* __restrict__ g, const float* __restrict__ bta,
                          float* __restrict__ scale, float* __restrict__ shift)
{
    int c = blockIdx.x;
    float s=0.f, sq=0.f;
    int Ntot = Bc*Lc;
    for (int idx=threadIdx.x; idx<Ntot; idx+=256){
        int b = idx / Lc, t = idx - b*Lc;
        float v = y[(b*DM+c)*Lc + t];
        s += v; sq = fmaf(v, v, sq);
    }
    #pragma unroll
    for (int off=32; off; off>>=1){ s += __shfl_down(s, off); sq += __shfl_down(sq, off); }
    __shared__ float rs[4], rq[4];
    int wid = threadIdx.x>>6, lane = threadIdx.x&63;
    if (lane==0){ rs[wid]=s; rq[wid]=sq; }
    __syncthreads();
    if (threadIdx.x==0){
        float S=rs[0]+rs[1]+rs[2]+rs[3];
        float Q=rq[0]+rq[1]+rq[2]+rq[3];
        float inv = 1.f/(float)Ntot;
        float mu = S*inv;
        float var = Q*inv - mu*mu;
        float sc = g[c]*rsqrtf(var + 1e-5f);
        scale[c]=sc; shift[c]=bta[c]-mu*sc;
    }
}

// ---------------- conv1: y0(8,128,4096) [BN applied on read] -> y1(8,128,2048), stride2 pad4, relu
__global__ __launch_bounds__(256) void k_conv1(
    const float* __restrict__ y0, const float* __restrict__ w,
    const float* __restrict__ bias,
    const float* __restrict__ sc0, const float* __restrict__ sh0,
    float* __restrict__ y1)
{
    __shared__ __align__(16) float in_s[DM][76];
    int b  = blockIdx.y;
    int t0 = blockIdx.x * 32;
    for (int idx=threadIdx.x; idx < DM*71; idx += 256){
        int ci = idx / 71, j = idx - ci*71;
        int tt = 2*t0 - 4 + j;
        float v = 0.f;
        if (tt >= 0 && tt < L1) v = fmaf(y0[(b*DM+ci)*L1 + tt], sc0[ci], sh0[ci]);
        in_s[ci][j] = v;
    }
    __syncthreads();
    int co = threadIdx.x & 127;
    int th = threadIdx.x >> 7;       // t-half: 0/1
    float acc[16];
    #pragma unroll
    for (int j=0;j<16;++j) acc[j]=bias[co];
    const float* wp = w + co*DM*KC;
    const int jbase = th*16;
    for (int ci=0; ci<DM; ++ci){
        float wv[KC];
        #pragma unroll
        for (int k=0;k<KC;++k) wv[k] = wp[ci*KC+k];
        const float4* rowp = reinterpret_cast<const float4*>(&in_s[ci][2*jbase]);
        float win[44];
        #pragma unroll
        for (int q=0;q<11;++q){
            float4 v4 = rowp[q];
            win[4*q]=v4.x; win[4*q+1]=v4.y; win[4*q+2]=v4.z; win[4*q+3]=v4.w;
        }
        #pragma unroll
        for (int j=0;j<16;++j)
            #pragma unroll
            for (int k=0;k<KC;++k)
                acc[j] = fmaf(wv[k], win[2*j+k], acc[j]);
    }
    #pragma unroll
    for (int j=0;j<16;++j){
        int t = t0 + jbase + j;
        y1[(b*DM+co)*L2c + t] = fmaxf(acc[j], 0.f);
    }
}

// ---------------- BN apply + transpose: y1(8,128,2048) -> h(8,2048,128)
__global__ void k_bnt(const float* __restrict__ y1, const float* __restrict__ sc,
                      const float* __restrict__ sh, float* __restrict__ h)
{
    __shared__ float tile[32][33];
    int b  = blockIdx.z;
    int c0 = blockIdx.x * 32;
    int t0 = blockIdx.y * 32;
    int tx = threadIdx.x & 31, ty = threadIdx.x >> 5;   // 8 rows
    for (int i=ty; i<32; i+=8)
        tile[i][tx] = fmaf(y1[(b*DM + c0+i)*L2c + t0+tx], sc[c0+i], sh[c0+i]);
    __syncthreads();
    for (int i=ty; i<32; i+=8)
        h[(b*L2c + t0+i)*DM + c0+tx] = tile[tx][i];
}

// ---------------- LayerNorm over D=128, one wave per token
__global__ void k_ln(const float* __restrict__ h, const float* __restrict__ g,
                     const float* __restrict__ bta, float* __restrict__ out)
{
    int tok  = blockIdx.x*4 + (threadIdx.x>>6);
    int lane = threadIdx.x & 63;
    const float2 v = reinterpret_cast<const float2*>(h + tok*DM)[lane];
    float s = v.x + v.y;
    #pragma unroll
    for (int off=32; off; off>>=1) s += __shfl_xor(s, off);
    float mu = s * (1.f/DM);
    float dx = v.x-mu, dy = v.y-mu;
    float q = dx*dx + dy*dy;
    #pragma unroll
    for (int off=32; off; off>>=1) q += __shfl_xor(q, off);
    float rstd = rsqrtf(q*(1.f/DM) + 1e-5f);
    float2 gg = reinterpret_cast<const float2*>(g)[lane];
    float2 bb = reinterpret_cast<const float2*>(bta)[lane];
    float2 o;
    o.x = fmaf(dx*rstd, gg.x, bb.x);
    o.y = fmaf(dy*rstd, gg.y, bb.y);
    reinterpret_cast<float2*>(out + tok*DM)[lane] = o;
}

// ---------------- generic fp32 GEMM: C[M,N] (+)= A[M,K] @ W[N,K]^T (+bias)(+act)
// BM=BN=64, BK=16, 256 threads, 4x4 microtile
template<int ACT, bool ACC, bool HASB>
__global__ __launch_bounds__(256) void k_gemm(
    const float* __restrict__ A, int lda,
    const float* __restrict__ W, int ldw,
    const float* __restrict__ bias,
    float* __restrict__ C, int ldc,
    int M, int N, int K)
{
    __shared__ __align__(16) float As[16][68];
    __shared__ __align__(16) float Ws[16][68];
    int m0 = blockIdx.x*64, n0 = blockIdx.y*64;
    int tx = threadIdx.x & 15, ty = threadIdx.x >> 4;
    float acc[4][4] = {};
    for (int k0 = 0; k0 < K; k0 += 16){
        __syncthreads();
        {
            int r = threadIdx.x >> 2;
            int cbase = (threadIdx.x & 3) * 4;
            const float* ap = A + (m0+r)*lda + k0;
            #pragma unroll
            for (int q=0;q<4;++q){
                int col = cbase+q;
                As[col][r] = (k0+col < K) ? ap[col] : 0.f;
            }
            const float* wp2 = W + (n0+r)*ldw + k0;
            bool nok = (n0 + r) < N;
            #pragma unroll
            for (int q=0;q<4;++q){
                int col = cbase+q;
                Ws[col][r] = (nok && (k0+col < K)) ? wp2[col] : 0.f;
            }
        }
        __syncthreads();
        #pragma unroll
        for (int kk=0; kk<16; ++kk){
            float4 a4 = *reinterpret_cast<const float4*>(&As[kk][ty*4]);
            float4 w4 = *reinterpret_cast<const float4*>(&Ws[kk][tx*4]);
            float av[4] = {a4.x,a4.y,a4.z,a4.w};
            float wv[4] = {w4.x,w4.y,w4.z,w4.w};
            #pragma unroll
            for (int i=0;i<4;++i)
                #pragma unroll
                for (int j=0;j<4;++j)
                    acc[i][j] = fmaf(av[i], wv[j], acc[i][j]);
        }
    }
    #pragma unroll
    for (int i=0;i<4;++i){
        int m = m0 + ty*4 + i;
        #pragma unroll
        for (int j=0;j<4;++j){
            int n = n0 + tx*4 + j;
            if (n < N){
                float v = acc[i][j];
                if (HASB) v += bias[n];
                if (ACT==1) v = softplusf_(v);
                float* cp = C + m*ldc + n;
                if (ACC) *cp += v; else *cp = v;
            }
        }
    }
}

// ---------------- depthwise causal conv (k=4) + bias + silu, from xz[:, :, :256]
__global__ void k_dwconv(const float* __restrict__ xz, const float* __restrict__ w,
                         const float* __restrict__ bias, float* __restrict__ xmc)
{
    int o = blockIdx.x*256 + threadIdx.x;   // (b*2048+t)*256 + d
    int d = o & 255, t = (o>>8) & 2047, b = o >> 19;
    float acc = bias[d];
    #pragma unroll
    for (int k=0;k<4;++k){
        int tt = t - 3 + k;
        if (tt >= 0) acc = fmaf(w[d*4+k], xz[(b*L2c+tt)*512 + d], acc);
    }
    xmc[o] = siluf_(acc);
}

// ---------------- chunked selective scan, pass 1: per-(b,d,chunk,n) transfer (P,Q)
// gid = ((b*NCH+c)*DI+d); lane n = state. 32768 groups, full occupancy.
__global__ __launch_bounds__(256) void k_scan1(
    const float* __restrict__ dtb, const float* __restrict__ xm,
    const float* __restrict__ xdbl, const float* __restrict__ A_log,
    float* __restrict__ Pb, float* __restrict__ Qb)
{
    int g = threadIdx.x >> 4, n = threadIdx.x & 15;
    int gid = blockIdx.x*16 + g;
    int d = gid & (DI-1), c = (gid >> 8) & (NCH-1), b = gid >> 12;
    float An = -__expf(A_log[d*DSt + n]);
    int t0 = c*TC;
    const float* dtp = dtb + (b*L2c + t0)*DI + d;
    const float* up  = xm  + (b*L2c + t0)*DI + d;
    const float* Bp  = xdbl + (b*L2c + t0)*40 + DTR + n;
    float P = 1.f, Q = 0.f;
    #pragma unroll 8
    for (int j=0;j<TC;++j){
        float dt = dtp[j*DI], u = up[j*DI], Bv = Bp[j*40];
        float dA = __expf(dt*An);
        P *= dA;
        Q = fmaf(dA, Q, dt*u*Bv);
    }
    Pb[gid*16+n] = P;
    Qb[gid*16+n] = Q;
}

// ---------------- pass 2 (stitch): sequential compose of NCH chunk transfers per (b,d,n)
__global__ void k_scan2(const float* __restrict__ Pb, const float* __restrict__ Qb,
                        float* __restrict__ Hin)
{
    int i = blockIdx.x*256 + threadIdx.x;   // (b*DI+d)*16+n, 32768 total
    int dn = i & 4095, b = i >> 12;
    float hv = 0.f;
    #pragma unroll
    for (int c=0;c<NCH;++c){
        int off = (b*NCH+c)*4096 + dn;
        Hin[off] = hv;
        hv = fmaf(Pb[off], hv, Qb[off]);
    }
}

// ---------------- pass 3: recompute h per chunk from stitched h_in, emit y
__global__ __launch_bounds__(256) void k_scan3(
    const float* __restrict__ dtb, const float* __restrict__ xm,
    const float* __restrict__ xdbl, const float* __restrict__ xz,
    const float* __restrict__ A_log, const float* __restrict__ Dp,
    const float* __restrict__ Hin, float* __restrict__ yb)
{
    int g = threadIdx.x >> 4, n = threadIdx.x & 15;
    int gid = blockIdx.x*16 + g;
    int d = gid & (DI-1), c = (gid >> 8) & (NCH-1), b = gid >> 12;
    float An = -__expf(A_log[d*DSt + n]);
    float Dv = Dp[d];
    int t0 = c*TC;
    const float* dtp = dtb + (b*L2c + t0)*DI + d;
    const float* up  = xm  + (b*L2c + t0)*DI + d;
    const float* zp  = xz  + (b*L2c + t0)*2*DI + DI + d;
    const float* Bp  = xdbl + (b*L2c + t0)*40 + DTR + n;
    const float* Cp  = Bp + DSt;
    float* yp = yb + (b*L2c + t0)*DI + d;
    float hv = Hin[gid*16+n];
    #pragma unroll 4
    for (int j=0;j<TC;++j){
        float dt = dtp[j*DI], u = up[j*DI], Bv = Bp[j*40], Cv = Cp[j*40];
        float dA = __expf(dt*An);
        hv = fmaf(dA, hv, dt*u*Bv);
        float p = hv*Cv;
        p += __shfl_xor(p,1); p += __shfl_xor(p,2);
        p += __shfl_xor(p,4); p += __shfl_xor(p,8);
        if (n == (j & 15)){
            float zv = zp[j*2*DI];
            yp[j*DI] = (p + u*Dv)*siluf_(zv);
        }
    }
}

// ---------------- final pool: mean over t of ln -> pooled(8,128)
__global__ void k_pool(const float* __restrict__ ln, float* __restrict__ pooled)
{
    __shared__ float sbuf[256];
    int b = blockIdx.x;
    int c = threadIdx.x & 127, half = threadIdx.x >> 7;
    float s = 0.f;
    for (int t = half; t < L2c; t += 2) s += ln[(b*L2c+t)*DM + c];
    sbuf[threadIdx.x] = s;
    __syncthreads();
    if (half == 0) pooled[b*DM+c] = (s + sbuf[threadIdx.x+128]) * (1.f/(float)L2c);
}

// ---------------- classifier: pooled(8,128) @ cls_w(100,128)^T + b -> out(8,100)
__global__ void k_cls(const float* __restrict__ pooled, const float* __restrict__ w,
                      const float* __restrict__ bias, float* __restrict__ out)
{
    int o = blockIdx.x*256 + threadIdx.x;
    if (o >= Bc*NC) return;
    int b = o/NC, n = o - b*NC;
    float s = bias[n];
    const float* pp = pooled + b*DM;
    const float* wp = w + n*DM;
    #pragma unroll 4
    for (int k=0;k<DM;++k) s = fmaf(pp[k], wp[k], s);
    out[o] = s;
}

extern "C" void kernel_launch(void* const* d_in, const int* in_sizes, int n_in,
                              void* d_out, int out_size, void* d_ws, size_t ws_size,
                              hipStream_t stream)
{
    const float* x        = (const float*)d_in[0];
    const float* conv0_w  = (const float*)d_in[1];
    const float* conv0_b  = (const float*)d_in[2];
    const float* bn0_g    = (const float*)d_in[3];
    const float* bn0_b    = (const float*)d_in[4];
    const float* conv1_w  = (const float*)d_in[5];
    const float* conv1_b  = (const float*)d_in[6];
    const float* bn1_g    = (const float*)d_in[7];
    const float* bn1_b    = (const float*)d_in[8];
    const float* ln_g     = (const float*)d_in[9];
    const float* ln_b     = (const float*)d_in[10];
    const float* in_proj_w= (const float*)d_in[11];
    const float* mconv_w  = (const float*)d_in[12];
    const float* mconv_b  = (const float*)d_in[13];
    const float* xproj_w  = (const float*)d_in[14];
    const float* dtproj_w = (const float*)d_in[15];
    const float* dtproj_b = (const float*)d_in[16];
    const float* A_log    = (const float*)d_in[17];
    const float* D_skip   = (const float*)d_in[18];
    const float* outproj_w= (const float*)d_in[19];
    const float* fnorm_g  = (const float*)d_in[20];
    const float* fnorm_b  = (const float*)d_in[21];
    const float* cls_w    = (const float*)d_in[22];
    const float* cls_b    = (const float*)d_in[23];
    float* out = (float*)d_out;

    float* ws = (float*)d_ws;
    float* sc0 = ws;        float* sh0 = ws+128;
    float* sc1 = ws+256;    float* sh1 = ws+384;
    float* h    = ws + 1024;              // 2,097,152
    float* ln   = h   + 2097152;          // 2,097,152
    float* xz   = ln  + 2097152;          // 8,388,608   (y0 aliases here)
    float* y0   = xz;
    float* xmc  = xz  + 8388608;          // 4,194,304   (y1 aliases here)
    float* y1   = xmc;
    float* xdbl = xmc + 4194304;          // 655,360
    float* dtb  = xdbl+ 655360;           // 4,194,304
    float* yb   = dtb + 4194304;          // 4,194,304
    float* pooled = yb + 4194304;         // 1,024

    // scan P/Q/Hin scratch aliases the ln buffer (dead during scan phase):
    // 3 x 524,288 floats = 1.5M floats < 2M float ln region.
    float* Pb  = ln;
    float* Qb  = ln + 524288;
    float* Hin = ln + 1048576;

    // conv stage
    k_conv0<<<16384, 256, 0, stream>>>(x, conv0_w, conv0_b, y0);
    k_bnstats<<<128, 256, 0, stream>>>(y0, L1, bn0_g, bn0_b, sc0, sh0);
    k_conv1<<<dim3(L2c/32, Bc), 256, 0, stream>>>(y0, conv1_w, conv1_b, sc0, sh0, y1);
    k_bnstats<<<128, 256, 0, stream>>>(y1, L2c, bn1_g, bn1_b, sc1, sh1);
    k_bnt<<<dim3(4, 64, Bc), 256, 0, stream>>>(y1, sc1, sh1, h);

    for (int i=0;i<NL;++i){
        k_ln<<<4096, 256, 0, stream>>>(h, ln_g + i*DM, ln_b + i*DM, ln);
        k_gemm<0,false,false><<<dim3(256, 8), 256, 0, stream>>>(
            ln, DM, in_proj_w + i*512*DM, DM, nullptr, xz, 512, 16384, 512, DM);
        k_dwconv<<<16384, 256, 0, stream>>>(xz, mconv_w + i*DI*4, mconv_b + i*DI, xmc);
        k_gemm<0,false,false><<<dim3(256, 1), 256, 0, stream>>>(
            xmc, DI, xproj_w + i*40*DI, DI, nullptr, xdbl, 40, 16384, 40, DI);
        k_gemm<1,false,true><<<dim3(256, 4), 256, 0, stream>>>(
            xdbl, 40, dtproj_w + i*DI*DTR, DTR, dtproj_b + i*DI, dtb, DI, 16384, DI, DTR);
        // chunked scan (ln buffer is dead here; reused as P/Q/Hin scratch)
        k_scan1<<<2048, 256, 0, stream>>>(dtb, xmc, xdbl, A_log + i*DI*DSt, Pb, Qb);
        k_scan2<<<128, 256, 0, stream>>>(Pb, Qb, Hin);
        k_scan3<<<2048, 256, 0, stream>>>(dtb, xmc, xdbl, xz,
            A_log + i*DI*DSt, D_skip + i*DI, Hin, yb);
        k_gemm<0,true,false><<<dim3(256, 2), 256, 0, stream>>>(
            yb, DI, outproj_w + i*DM*DI, DI, nullptr, h, DM, 16384, DM, DI);
    }

    k_ln<<<4096, 256, 0, stream>>>(h, fnorm_g, fnorm_b, ln);
    k_pool<<<Bc, 256, 0, stream>>>(ln, pooled);
    k_cls<<<4, 256, 0, stream>>>(pooled, cls_w, cls_b, out);
}

// Round 6
// 1672.513 us; speedup vs baseline: 2.0264x; 1.1417x over previous
//
#include <hip/hip_runtime.h>
#include <hip/hip_bf16.h>

#define DEV __device__ __forceinline__

static constexpr int Bc = 8;
static constexpr int L0 = 8192, L1 = 4096, L2c = 2048;
static constexpr int DM = 128, DI = 256, DSt = 16, DTR = 8, NL = 4, NC = 100;
static constexpr int KC = 9;
static constexpr int TC = 128, NCH = 16;   // scan chunking: 16 chunks of 128 steps
static constexpr int PCH = 32;             // pool chunking: 32 chunks of 64 tokens

DEV float sigmoidf_(float x){ return 1.f/(1.f+__expf(-x)); }
DEV float siluf_(float x){ return x*sigmoidf_(x); }
DEV float softplusf_(float x){ return (x>20.f)? x : log1pf(__expf(x)); }

// ---------------- conv0: x(8,4,8192) -> y0(8,128,4096), stride2 pad4, relu
__global__ void k_conv0(const float* __restrict__ x, const float* __restrict__ w,
                        const float* __restrict__ bias, float* __restrict__ y)
{
    int o = blockIdx.x*256 + threadIdx.x;           // (b*128+co)*4096 + t
    int t  = o & (L1-1);
    int co = (o >> 12) & (DM-1);
    int b  = o >> 19;
    const float* wp = w + co*4*KC;
    float acc = bias[co];
    int base = 2*t - 4;
    #pragma unroll
    for (int ci=0; ci<4; ++ci){
        const float* xp = x + (b*4+ci)*L0;
        #pragma unroll
        for (int k=0;k<KC;++k){
            int tt = base + k;
            if (tt >= 0 && tt < L0) acc = fmaf(wp[ci*KC+k], xp[tt], acc);
        }
    }
    y[o] = fmaxf(acc, 0.f);
}

// ---------------- BN train stats -> scale/shift per channel
__global__ void k_bnstats(const float* __restrict__ y, int Lc,
                          const float* __restrict__ g, const float* __restrict__ bta,
                          float* __restrict__ scale, float* __restrict__ shift)
{
    int c = blockIdx.x;
    float s=0.f, sq=0.f;
    int Ntot = Bc*Lc;
    for (int idx=threadIdx.x; idx<Ntot; idx+=256){
        int b = idx / Lc, t = idx - b*Lc;
        float v = y[(b*DM+c)*Lc + t];
        s += v; sq = fmaf(v, v, sq);
    }
    #pragma unroll
    for (int off=32; off; off>>=1){ s += __shfl_down(s, off); sq += __shfl_down(sq, off); }
    __shared__ float rs[4], rq[4];
    int wid = threadIdx.x>>6, lane = threadIdx.x&63;
    if (lane==0){ rs[wid]=s; rq[wid]=sq; }
    __syncthreads();
    if (threadIdx.x==0){
        float S=rs[0]+rs[1]+rs[2]+rs[3];
        float Q=rq[0]+rq[1]+rq[2]+rq[3];
        float inv = 1.f/(float)Ntot;
        float mu = S*inv;
        float var = Q*inv - mu*mu;
        float sc = g[c]*rsqrtf(var + 1e-5f);
        scale[c]=sc; shift[c]=bta[c]-mu*sc;
    }
}

// ---------------- conv1: y0(8,128,4096) [BN applied on read] -> y1(8,128,2048), stride2 pad4, relu
__global__ __launch_bounds__(256) void k_conv1(
    const float* __restrict__ y0, const float* __restrict__ w,
    const float* __restrict__ bias,
    const float* __restrict__ sc0, const float* __restrict__ sh0,
    float* __restrict__ y1)
{
    __shared__ __align__(16) float in_s[DM][76];
    int b  = blockIdx.y;
    int t0 = blockIdx.x * 32;
    for (int idx=threadIdx.x; idx < DM*71; idx += 256){
        int ci = idx / 71, j = idx - ci*71;
        int tt = 2*t0 - 4 + j;
        float v = 0.f;
        if (tt >= 0 && tt < L1) v = fmaf(y0[(b*DM+ci)*L1 + tt], sc0[ci], sh0[ci]);
        in_s[ci][j] = v;
    }
    __syncthreads();
    int co = threadIdx.x & 127;
    int th = threadIdx.x >> 7;       // t-half: 0/1
    float acc[16];
    #pragma unroll
    for (int j=0;j<16;++j) acc[j]=bias[co];
    const float* wp = w + co*DM*KC;
    const int jbase = th*16;
    for (int ci=0; ci<DM; ++ci){
        float wv[KC];
        #pragma unroll
        for (int k=0;k<KC;++k) wv[k] = wp[ci*KC+k];
        const float4* rowp = reinterpret_cast<const float4*>(&in_s[ci][2*jbase]);
        float win[44];
        #pragma unroll
        for (int q=0;q<11;++q){
            float4 v4 = rowp[q];
            win[4*q]=v4.x; win[4*q+1]=v4.y; win[4*q+2]=v4.z; win[4*q+3]=v4.w;
        }
        #pragma unroll
        for (int j=0;j<16;++j)
            #pragma unroll
            for (int k=0;k<KC;++k)
                acc[j] = fmaf(wv[k], win[2*j+k], acc[j]);
    }
    #pragma unroll
    for (int j=0;j<16;++j){
        int t = t0 + jbase + j;
        y1[(b*DM+co)*L2c + t] = fmaxf(acc[j], 0.f);
    }
}

// ---------------- BN apply + transpose: y1(8,128,2048) -> h(8,2048,128)
__global__ void k_bnt(const float* __restrict__ y1, const float* __restrict__ sc,
                      const float* __restrict__ sh, float* __restrict__ h)
{
    __shared__ float tile[32][33];
    int b  = blockIdx.z;
    int c0 = blockIdx.x * 32;
    int t0 = blockIdx.y * 32;
    int tx = threadIdx.x & 31, ty = threadIdx.x >> 5;   // 8 rows
    for (int i=ty; i<32; i+=8)
        tile[i][tx] = fmaf(y1[(b*DM + c0+i)*L2c + t0+tx], sc[c0+i], sh[c0+i]);
    __syncthreads();
    for (int i=ty; i<32; i+=8)
        h[(b*L2c + t0+i)*DM + c0+tx] = tile[tx][i];
}

// ---------------- LayerNorm over D=128, one wave per token
__global__ void k_ln(const float* __restrict__ h, const float* __restrict__ g,
                     const float* __restrict__ bta, float* __restrict__ out)
{
    int tok  = blockIdx.x*4 + (threadIdx.x>>6);
    int lane = threadIdx.x & 63;
    const float2 v = reinterpret_cast<const float2*>(h + tok*DM)[lane];
    float s = v.x + v.y;
    #pragma unroll
    for (int off=32; off; off>>=1) s += __shfl_xor(s, off);
    float mu = s * (1.f/DM);
    float dx = v.x-mu, dy = v.y-mu;
    float q = dx*dx + dy*dy;
    #pragma unroll
    for (int off=32; off; off>>=1) q += __shfl_xor(q, off);
    float rstd = rsqrtf(q*(1.f/DM) + 1e-5f);
    float2 gg = reinterpret_cast<const float2*>(g)[lane];
    float2 bb = reinterpret_cast<const float2*>(bta)[lane];
    float2 o;
    o.x = fmaf(dx*rstd, gg.x, bb.x);
    o.y = fmaf(dy*rstd, gg.y, bb.y);
    reinterpret_cast<float2*>(out + tok*DM)[lane] = o;
}

// ---------------- generic fp32 GEMM: C[M,N] (+)= A[M,K] @ W[N,K]^T (+bias)(+act)
// BM=BN=64, BK=16, 256 threads, 4x4 microtile
template<int ACT, bool ACC, bool HASB>
__global__ __launch_bounds__(256) void k_gemm(
    const float* __restrict__ A, int lda,
    const float* __restrict__ W, int ldw,
    const float* __restrict__ bias,
    float* __restrict__ C, int ldc,
    int M, int N, int K)
{
    __shared__ __align__(16) float As[16][68];
    __shared__ __align__(16) float Ws[16][68];
    int m0 = blockIdx.x*64, n0 = blockIdx.y*64;
    int tx = threadIdx.x & 15, ty = threadIdx.x >> 4;
    float acc[4][4] = {};
    for (int k0 = 0; k0 < K; k0 += 16){
        __syncthreads();
        {
            int r = threadIdx.x >> 2;
            int cbase = (threadIdx.x & 3) * 4;
            const float* ap = A + (m0+r)*lda + k0;
            #pragma unroll
            for (int q=0;q<4;++q){
                int col = cbase+q;
                As[col][r] = (k0+col < K) ? ap[col] : 0.f;
            }
            const float* wp2 = W + (n0+r)*ldw + k0;
            bool nok = (n0 + r) < N;
            #pragma unroll
            for (int q=0;q<4;++q){
                int col = cbase+q;
                Ws[col][r] = (nok && (k0+col < K)) ? wp2[col] : 0.f;
            }
        }
        __syncthreads();
        #pragma unroll
        for (int kk=0; kk<16; ++kk){
            float4 a4 = *reinterpret_cast<const float4*>(&As[kk][ty*4]);
            float4 w4 = *reinterpret_cast<const float4*>(&Ws[kk][tx*4]);
            float av[4] = {a4.x,a4.y,a4.z,a4.w};
            float wv[4] = {w4.x,w4.y,w4.z,w4.w};
            #pragma unroll
            for (int i=0;i<4;++i)
                #pragma unroll
                for (int j=0;j<4;++j)
                    acc[i][j] = fmaf(av[i], wv[j], acc[i][j]);
        }
    }
    #pragma unroll
    for (int i=0;i<4;++i){
        int m = m0 + ty*4 + i;
        #pragma unroll
        for (int j=0;j<4;++j){
            int n = n0 + tx*4 + j;
            if (n < N){
                float v = acc[i][j];
                if (HASB) v += bias[n];
                if (ACT==1) v = softplusf_(v);
                float* cp = C + m*ldc + n;
                if (ACC) *cp += v; else *cp = v;
            }
        }
    }
}

// ---------------- depthwise causal conv (k=4) + bias + silu, from xz[:, :, :256]
__global__ void k_dwconv(const float* __restrict__ xz, const float* __restrict__ w,
                         const float* __restrict__ bias, float* __restrict__ xmc)
{
    int o = blockIdx.x*256 + threadIdx.x;   // (b*2048+t)*256 + d
    int d = o & 255, t = (o>>8) & 2047, b = o >> 19;
    float acc = bias[d];
    #pragma unroll
    for (int k=0;k<4;++k){
        int tt = t - 3 + k;
        if (tt >= 0) acc = fmaf(w[d*4+k], xz[(b*L2c+tt)*512 + d], acc);
    }
    xmc[o] = siluf_(acc);
}

// ---------------- chunked selective scan, pass 1: per-(b,d,chunk,n) transfer (P,Q)
__global__ __launch_bounds__(256) void k_scan1(
    const float* __restrict__ dtb, const float* __restrict__ xm,
    const float* __restrict__ xdbl, const float* __restrict__ A_log,
    float* __restrict__ Pb, float* __restrict__ Qb)
{
    int g = threadIdx.x >> 4, n = threadIdx.x & 15;
    int gid = blockIdx.x*16 + g;
    int d = gid & (DI-1), c = (gid >> 8) & (NCH-1), b = gid >> 12;
    float An = -__expf(A_log[d*DSt + n]);
    int t0 = c*TC;
    const float* dtp = dtb + (b*L2c + t0)*DI + d;
    const float* up  = xm  + (b*L2c + t0)*DI + d;
    const float* Bp  = xdbl + (b*L2c + t0)*40 + DTR + n;
    float P = 1.f, Q = 0.f;
    #pragma unroll 8
    for (int j=0;j<TC;++j){
        float dt = dtp[j*DI], u = up[j*DI], Bv = Bp[j*40];
        float dA = __expf(dt*An);
        P *= dA;
        Q = fmaf(dA, Q, dt*u*Bv);
    }
    Pb[gid*16+n] = P;
    Qb[gid*16+n] = Q;
}

// ---------------- pass 2 (stitch): sequential compose of NCH chunk transfers per (b,d,n)
__global__ void k_scan2(const float* __restrict__ Pb, const float* __restrict__ Qb,
                        float* __restrict__ Hin)
{
    int i = blockIdx.x*256 + threadIdx.x;   // (b*DI+d)*16+n, 32768 total
    int dn = i & 4095, b = i >> 12;
    float hv = 0.f;
    #pragma unroll
    for (int c=0;c<NCH;++c){
        int off = (b*NCH+c)*4096 + dn;
        Hin[off] = hv;
        hv = fmaf(Pb[off], hv, Qb[off]);
    }
}

// ---------------- pass 3: recompute h per chunk from stitched h_in, emit y
__global__ __launch_bounds__(256) void k_scan3(
    const float* __restrict__ dtb, const float* __restrict__ xm,
    const float* __restrict__ xdbl, const float* __restrict__ xz,
    const float* __restrict__ A_log, const float* __restrict__ Dp,
    const float* __restrict__ Hin, float* __restrict__ yb)
{
    int g = threadIdx.x >> 4, n = threadIdx.x & 15;
    int gid = blockIdx.x*16 + g;
    int d = gid & (DI-1), c = (gid >> 8) & (NCH-1), b = gid >> 12;
    float An = -__expf(A_log[d*DSt + n]);
    float Dv = Dp[d];
    int t0 = c*TC;
    const float* dtp = dtb + (b*L2c + t0)*DI + d;
    const float* up  = xm  + (b*L2c + t0)*DI + d;
    const float* zp  = xz  + (b*L2c + t0)*2*DI + DI + d;
    const float* Bp  = xdbl + (b*L2c + t0)*40 + DTR + n;
    const float* Cp  = Bp + DSt;
    float* yp = yb + (b*L2c + t0)*DI + d;
    float hv = Hin[gid*16+n];
    #pragma unroll 4
    for (int j=0;j<TC;++j){
        float dt = dtp[j*DI], u = up[j*DI], Bv = Bp[j*40], Cv = Cp[j*40];
        float dA = __expf(dt*An);
        hv = fmaf(dA, hv, dt*u*Bv);
        float p = hv*Cv;
        p += __shfl_xor(p,1); p += __shfl_xor(p,2);
        p += __shfl_xor(p,4); p += __shfl_xor(p,8);
        if (n == (j & 15)){
            float zv = zp[j*2*DI];
            yp[j*DI] = (p + u*Dv)*siluf_(zv);
        }
    }
}

// ---------------- pool pass 1: partial mean over 64-token chunks
// grid (PCH, Bc), 256 thr = 2 t-halves x 128 c
__global__ void k_pool1(const float* __restrict__ ln, float* __restrict__ partial)
{
    __shared__ float sbuf[256];
    int ch = blockIdx.x, b = blockIdx.y;
    int c = threadIdx.x & 127, half = threadIdx.x >> 7;
    int t0 = ch*(L2c/PCH);
    float s = 0.f;
    for (int j = half; j < L2c/PCH; j += 2)
        s += ln[(b*L2c + t0 + j)*DM + c];
    sbuf[threadIdx.x] = s;
    __syncthreads();
    if (half == 0)
        partial[(b*PCH + ch)*DM + c] = s + sbuf[threadIdx.x + 128];
}

// ---------------- pool pass 2: reduce PCH partials -> pooled(8,128)
__global__ void k_pool2(const float* __restrict__ partial, float* __restrict__ pooled)
{
    int i = blockIdx.x*256 + threadIdx.x;   // b*128+c, 1024 total
    if (i >= Bc*DM) return;
    int b = i >> 7, c = i & 127;
    float s = 0.f;
    #pragma unroll
    for (int ch=0; ch<PCH; ++ch)
        s += partial[(b*PCH + ch)*DM + c];
    pooled[i] = s * (1.f/(float)L2c);
}

// ---------------- classifier: pooled(8,128) @ cls_w(100,128)^T + b -> out(8,100)
__global__ void k_cls(const float* __restrict__ pooled, const float* __restrict__ w,
                      const float* __restrict__ bias, float* __restrict__ out)
{
    int o = blockIdx.x*256 + threadIdx.x;
    if (o >= Bc*NC) return;
    int b = o/NC, n = o - b*NC;
    float s = bias[n];
    const float* pp = pooled + b*DM;
    const float* wp = w + n*DM;
    #pragma unroll 4
    for (int k=0;k<DM;++k) s = fmaf(pp[k], wp[k], s);
    out[o] = s;
}

extern "C" void kernel_launch(void* const* d_in, const int* in_sizes, int n_in,
                              void* d_out, int out_size, void* d_ws, size_t ws_size,
                              hipStream_t stream)
{
    const float* x        = (const float*)d_in[0];
    const float* conv0_w  = (const float*)d_in[1];
    const float* conv0_b  = (const float*)d_in[2];
    const float* bn0_g    = (const float*)d_in[3];
    const float* bn0_b    = (const float*)d_in[4];
    const float* conv1_w  = (const float*)d_in[5];
    const float* conv1_b  = (const float*)d_in[6];
    const float* bn1_g    = (const float*)d_in[7];
    const float* bn1_b    = (const float*)d_in[8];
    const float* ln_g     = (const float*)d_in[9];
    const float* ln_b     = (const float*)d_in[10];
    const float* in_proj_w= (const float*)d_in[11];
    const float* mconv_w  = (const float*)d_in[12];
    const float* mconv_b  = (const float*)d_in[13];
    const float* xproj_w  = (const float*)d_in[14];
    const float* dtproj_w = (const float*)d_in[15];
    const float* dtproj_b = (const float*)d_in[16];
    const float* A_log    = (const float*)d_in[17];
    const float* D_skip   = (const float*)d_in[18];
    const float* outproj_w= (const float*)d_in[19];
    const float* fnorm_g  = (const float*)d_in[20];
    const float* fnorm_b  = (const float*)d_in[21];
    const float* cls_w    = (const float*)d_in[22];
    const float* cls_b    = (const float*)d_in[23];
    float* out = (float*)d_out;

    float* ws = (float*)d_ws;
    float* sc0 = ws;        float* sh0 = ws+128;
    float* sc1 = ws+256;    float* sh1 = ws+384;
    float* h    = ws + 1024;              // 2,097,152
    float* ln   = h   + 2097152;          // 2,097,152
    float* xz   = ln  + 2097152;          // 8,388,608   (y0 aliases here)
    float* y0   = xz;
    float* xmc  = xz  + 8388608;          // 4,194,304   (y1 aliases here)
    float* y1   = xmc;
    float* xdbl = xmc + 4194304;          // 655,360
    float* dtb  = xdbl+ 655360;           // 4,194,304
    float* yb   = dtb + 4194304;          // 4,194,304
    float* pooled = yb + 4194304;         // 1,024
    float* partial = pooled + 1024;       // 4,096 (PCH*Bc*DM)

    // scan P/Q/Hin scratch aliases the ln buffer (dead during scan phase)
    float* Pb  = ln;
    float* Qb  = ln + 524288;
    float* Hin = ln + 1048576;

    // conv stage
    k_conv0<<<16384, 256, 0, stream>>>(x, conv0_w, conv0_b, y0);
    k_bnstats<<<128, 256, 0, stream>>>(y0, L1, bn0_g, bn0_b, sc0, sh0);
    k_conv1<<<dim3(L2c/32, Bc), 256, 0, stream>>>(y0, conv1_w, conv1_b, sc0, sh0, y1);
    k_bnstats<<<128, 256, 0, stream>>>(y1, L2c, bn1_g, bn1_b, sc1, sh1);
    k_bnt<<<dim3(4, 64, Bc), 256, 0, stream>>>(y1, sc1, sh1, h);

    for (int i=0;i<NL;++i){
        k_ln<<<4096, 256, 0, stream>>>(h, ln_g + i*DM, ln_b + i*DM, ln);
        k_gemm<0,false,false><<<dim3(256, 8), 256, 0, stream>>>(
            ln, DM, in_proj_w + i*512*DM, DM, nullptr, xz, 512, 16384, 512, DM);
        k_dwconv<<<16384, 256, 0, stream>>>(xz, mconv_w + i*DI*4, mconv_b + i*DI, xmc);
        k_gemm<0,false,false><<<dim3(256, 1), 256, 0, stream>>>(
            xmc, DI, xproj_w + i*40*DI, DI, nullptr, xdbl, 40, 16384, 40, DI);
        k_gemm<1,false,true><<<dim3(256, 4), 256, 0, stream>>>(
            xdbl, 40, dtproj_w + i*DI*DTR, DTR, dtproj_b + i*DI, dtb, DI, 16384, DI, DTR);
        k_scan1<<<2048, 256, 0, stream>>>(dtb, xmc, xdbl, A_log + i*DI*DSt, Pb, Qb);
        k_scan2<<<128, 256, 0, stream>>>(Pb, Qb, Hin);
        k_scan3<<<2048, 256, 0, stream>>>(dtb, xmc, xdbl, xz,
            A_log + i*DI*DSt, D_skip + i*DI, Hin, yb);
        k_gemm<0,true,false><<<dim3(256, 2), 256, 0, stream>>>(
            yb, DI, outproj_w + i*DM*DI, DI, nullptr, h, DM, 16384, DM, DI);
    }

    k_ln<<<4096, 256, 0, stream>>>(h, fnorm_g, fnorm_b, ln);
    k_pool1<<<dim3(PCH, Bc), 256, 0, stream>>>(ln, partial);
    k_pool2<<<4, 256, 0, stream>>>(partial, pooled);
    k_cls<<<4, 256, 0, stream>>>(pooled, cls_w, cls_b, out);
}

// Round 7
// 1573.184 us; speedup vs baseline: 2.1543x; 1.0631x over previous
//
#include <hip/hip_runtime.h>
#include <hip/hip_bf16.h>

#define DEV __device__ __forceinline__

static constexpr int Bc = 8;
static constexpr int L0 = 8192, L1 = 4096, L2c = 2048;
static constexpr int DM = 128, DI = 256, DSt = 16, DTR = 8, NL = 4, NC = 100;
static constexpr int KC = 9;
static constexpr int TC = 128, NCH = 16;   // scan chunking
static constexpr int PCH = 32;             // pool chunking

DEV float sigmoidf_(float x){ return 1.f/(1.f+__expf(-x)); }
DEV float siluf_(float x){ return x*sigmoidf_(x); }
DEV float softplusf_(float x){ return (x>20.f)? x : log1pf(__expf(x)); }

// ---------------- conv0: x(8,4,8192) -> y0(8,128,4096), stride2 pad4, relu
__global__ void k_conv0(const float* __restrict__ x, const float* __restrict__ w,
                        const float* __restrict__ bias, float* __restrict__ y)
{
    int o = blockIdx.x*256 + threadIdx.x;           // (b*128+co)*4096 + t
    int t  = o & (L1-1);
    int co = (o >> 12) & (DM-1);
    int b  = o >> 19;
    const float* wp = w + co*4*KC;
    float acc = bias[co];
    int base = 2*t - 4;
    #pragma unroll
    for (int ci=0; ci<4; ++ci){
        const float* xp = x + (b*4+ci)*L0;
        #pragma unroll
        for (int k=0;k<KC;++k){
            int tt = base + k;
            if (tt >= 0 && tt < L0) acc = fmaf(wp[ci*KC+k], xp[tt], acc);
        }
    }
    y[o] = fmaxf(acc, 0.f);
}

// ---------------- BN train stats -> scale/shift per channel
__global__ void k_bnstats(const float* __restrict__ y, int Lc,
                          const float* __restrict__ g, const float* __restrict__ bta,
                          float* __restrict__ scale, float* __restrict__ shift)
{
    int c = blockIdx.x;
    float s=0.f, sq=0.f;
    int Ntot = Bc*Lc;
    for (int idx=threadIdx.x; idx<Ntot; idx+=256){
        int b = idx / Lc, t = idx - b*Lc;
        float v = y[(b*DM+c)*Lc + t];
        s += v; sq = fmaf(v, v, sq);
    }
    #pragma unroll
    for (int off=32; off; off>>=1){ s += __shfl_down(s, off); sq += __shfl_down(sq, off); }
    __shared__ float rs[4], rq[4];
    int wid = threadIdx.x>>6, lane = threadIdx.x&63;
    if (lane==0){ rs[wid]=s; rq[wid]=sq; }
    __syncthreads();
    if (threadIdx.x==0){
        float S=rs[0]+rs[1]+rs[2]+rs[3];
        float Q=rq[0]+rq[1]+rq[2]+rq[3];
        float inv = 1.f/(float)Ntot;
        float mu = S*inv;
        float var = Q*inv - mu*mu;
        float sc = g[c]*rsqrtf(var + 1e-5f);
        scale[c]=sc; shift[c]=bta[c]-mu*sc;
    }
}

// ---------------- conv1: 512 threads = 128co x 4 t-quarters, 8 outputs each
__global__ __launch_bounds__(512) void k_conv1(
    const float* __restrict__ y0, const float* __restrict__ w,
    const float* __restrict__ bias,
    const float* __restrict__ sc0, const float* __restrict__ sh0,
    float* __restrict__ y1)
{
    __shared__ __align__(16) float in_s[DM][76];
    int b  = blockIdx.y;
    int t0 = blockIdx.x * 32;
    for (int idx=threadIdx.x; idx < DM*71; idx += 512){
        int ci = idx / 71, j = idx - ci*71;
        int tt = 2*t0 - 4 + j;
        float v = 0.f;
        if (tt >= 0 && tt < L1) v = fmaf(y0[(b*DM+ci)*L1 + tt], sc0[ci], sh0[ci]);
        in_s[ci][j] = v;
    }
    __syncthreads();
    int co = threadIdx.x & 127;
    int th = threadIdx.x >> 7;       // t-quarter: 0..3
    float acc[8];
    #pragma unroll
    for (int j=0;j<8;++j) acc[j]=bias[co];
    const float* wp = w + co*DM*KC;
    const int jbase = th*8;
    for (int ci=0; ci<DM; ++ci){
        float wv[KC];
        #pragma unroll
        for (int k=0;k<KC;++k) wv[k] = wp[ci*KC+k];
        const float4* rowp = reinterpret_cast<const float4*>(&in_s[ci][2*jbase]);
        float win[24];
        #pragma unroll
        for (int q=0;q<6;++q){
            float4 v4 = rowp[q];
            win[4*q]=v4.x; win[4*q+1]=v4.y; win[4*q+2]=v4.z; win[4*q+3]=v4.w;
        }
        #pragma unroll
        for (int j=0;j<8;++j)
            #pragma unroll
            for (int k=0;k<KC;++k)
                acc[j] = fmaf(wv[k], win[2*j+k], acc[j]);
    }
    #pragma unroll
    for (int j=0;j<8;++j){
        int t = t0 + jbase + j;
        y1[(b*DM+co)*L2c + t] = fmaxf(acc[j], 0.f);
    }
}

// ---------------- BN apply + transpose: y1(8,128,2048) -> h(8,2048,128)
__global__ void k_bnt(const float* __restrict__ y1, const float* __restrict__ sc,
                      const float* __restrict__ sh, float* __restrict__ h)
{
    __shared__ float tile[32][33];
    int b  = blockIdx.z;
    int c0 = blockIdx.x * 32;
    int t0 = blockIdx.y * 32;
    int tx = threadIdx.x & 31, ty = threadIdx.x >> 5;   // 8 rows
    for (int i=ty; i<32; i+=8)
        tile[i][tx] = fmaf(y1[(b*DM + c0+i)*L2c + t0+tx], sc[c0+i], sh[c0+i]);
    __syncthreads();
    for (int i=ty; i<32; i+=8)
        h[(b*L2c + t0+i)*DM + c0+tx] = tile[tx][i];
}

// ---------------- LayerNorm over D=128, one wave per token
__global__ void k_ln(const float* __restrict__ h, const float* __restrict__ g,
                     const float* __restrict__ bta, float* __restrict__ out)
{
    int tok  = blockIdx.x*4 + (threadIdx.x>>6);
    int lane = threadIdx.x & 63;
    const float2 v = reinterpret_cast<const float2*>(h + tok*DM)[lane];
    float s = v.x + v.y;
    #pragma unroll
    for (int off=32; off; off>>=1) s += __shfl_xor(s, off);
    float mu = s * (1.f/DM);
    float dx = v.x-mu, dy = v.y-mu;
    float q = dx*dx + dy*dy;
    #pragma unroll
    for (int off=32; off; off>>=1) q += __shfl_xor(q, off);
    float rstd = rsqrtf(q*(1.f/DM) + 1e-5f);
    float2 gg = reinterpret_cast<const float2*>(g)[lane];
    float2 bb = reinterpret_cast<const float2*>(bta)[lane];
    float2 o;
    o.x = fmaf(dx*rstd, gg.x, bb.x);
    o.y = fmaf(dy*rstd, gg.y, bb.y);
    reinterpret_cast<float2*>(out + tok*DM)[lane] = o;
}

// ---------------- fp32 GEMM: C[M,N] (+)= A[M,K] @ W[N,K]^T
// BM=128, BN=64, BK=16, 256 threads, 8x4 microtile. K must be multiple of 16.
template<bool ACC>
__global__ __launch_bounds__(256) void k_gemm(
    const float* __restrict__ A, int lda,
    const float* __restrict__ W, int ldw,
    float* __restrict__ C, int ldc,
    int M, int N, int K)
{
    __shared__ __align__(16) float As[16][132];
    __shared__ __align__(16) float Ws[16][68];
    int m0 = blockIdx.x*128, n0 = blockIdx.y*64;
    int tx = threadIdx.x & 15, ty = threadIdx.x >> 4;
    float acc[8][4] = {};
    for (int k0 = 0; k0 < K; k0 += 16){
        __syncthreads();
        {
            int ra = threadIdx.x >> 1;
            int ca = (threadIdx.x & 1) * 8;
            const float* ap = A + (m0+ra)*lda + k0 + ca;
            #pragma unroll
            for (int q=0;q<8;++q) As[ca+q][ra] = ap[q];
            int rw = threadIdx.x >> 2;
            int cw = (threadIdx.x & 3) * 4;
            const float* wp2 = W + (n0+rw)*ldw + k0 + cw;
            bool nok = (n0 + rw) < N;
            #pragma unroll
            for (int q=0;q<4;++q) Ws[cw+q][rw] = nok ? wp2[q] : 0.f;
        }
        __syncthreads();
        #pragma unroll
        for (int kk=0; kk<16; ++kk){
            float4 a0 = *reinterpret_cast<const float4*>(&As[kk][ty*8]);
            float4 a1 = *reinterpret_cast<const float4*>(&As[kk][ty*8+4]);
            float4 w4 = *reinterpret_cast<const float4*>(&Ws[kk][tx*4]);
            float av[8] = {a0.x,a0.y,a0.z,a0.w,a1.x,a1.y,a1.z,a1.w};
            float wv[4] = {w4.x,w4.y,w4.z,w4.w};
            #pragma unroll
            for (int i=0;i<8;++i)
                #pragma unroll
                for (int j=0;j<4;++j)
                    acc[i][j] = fmaf(av[i], wv[j], acc[i][j]);
        }
    }
    #pragma unroll
    for (int i=0;i<8;++i){
        int m = m0 + ty*8 + i;
        #pragma unroll
        for (int j=0;j<4;++j){
            int n = n0 + tx*4 + j;
            if (n < N){
                float* cp = C + m*ldc + n;
                if (ACC) *cp += acc[i][j]; else *cp = acc[i][j];
            }
        }
    }
}

// ---------------- depthwise causal conv (k=4) + bias + silu, from xz[:, :, :256]
__global__ void k_dwconv(const float* __restrict__ xz, const float* __restrict__ w,
                         const float* __restrict__ bias, float* __restrict__ xmc)
{
    int o = blockIdx.x*256 + threadIdx.x;   // (b*2048+t)*256 + d
    int d = o & 255, t = (o>>8) & 2047, b = o >> 19;
    float acc = bias[d];
    #pragma unroll
    for (int k=0;k<4;++k){
        int tt = t - 3 + k;
        if (tt >= 0) acc = fmaf(w[d*4+k], xz[(b*L2c+tt)*512 + d], acc);
    }
    xmc[o] = siluf_(acc);
}

// ---------------- scan pass 1 with fused dt-projection.
// Lane n computes softplus dt for step j==n (mod 16); __shfl distributes.
__global__ __launch_bounds__(256) void k_scan1(
    const float* __restrict__ xm, const float* __restrict__ xdbl,
    const float* __restrict__ dtw, const float* __restrict__ dtbias,
    const float* __restrict__ A_log,
    float* __restrict__ Pb, float* __restrict__ Qb)
{
    int g = threadIdx.x >> 4, n = threadIdx.x & 15;
    int gid = blockIdx.x*16 + g;
    int d = gid & (DI-1), c = (gid >> 8) & (NCH-1), b = gid >> 12;
    float An = -__expf(A_log[d*DSt + n]);
    const float4 w0 = *reinterpret_cast<const float4*>(dtw + d*DTR);
    const float4 w1 = *reinterpret_cast<const float4*>(dtw + d*DTR + 4);
    const float bd = dtbias[d];
    int t0 = c*TC;
    const float* up  = xm  + (b*L2c + t0)*DI + d;
    const float* xrow = xdbl + (b*L2c + t0)*40;
    int srcbase = threadIdx.x & 0x30;   // group base lane within wave
    float P = 1.f, Q = 0.f;
    for (int jb=0; jb<TC; jb+=16){
        const float* xr = xrow + (jb+n)*40;
        float4 r0 = *reinterpret_cast<const float4*>(xr);
        float4 r1 = *reinterpret_cast<const float4*>(xr+4);
        float dtv = bd;
        dtv = fmaf(r0.x,w0.x, dtv); dtv = fmaf(r0.y,w0.y, dtv);
        dtv = fmaf(r0.z,w0.z, dtv); dtv = fmaf(r0.w,w0.w, dtv);
        dtv = fmaf(r1.x,w1.x, dtv); dtv = fmaf(r1.y,w1.y, dtv);
        dtv = fmaf(r1.z,w1.z, dtv); dtv = fmaf(r1.w,w1.w, dtv);
        dtv = softplusf_(dtv);
        #pragma unroll
        for (int jj=0; jj<16; ++jj){
            float dtj = __shfl(dtv, srcbase + jj);
            float u  = up[(jb+jj)*DI];
            float Bv = xrow[(jb+jj)*40 + DTR + n];
            float dA = __expf(dtj*An);
            P *= dA;
            Q = fmaf(dA, Q, dtj*u*Bv);
        }
    }
    Pb[gid*16+n] = P;
    Qb[gid*16+n] = Q;
}

// ---------------- pass 2 (stitch)
__global__ void k_scan2(const float* __restrict__ Pb, const float* __restrict__ Qb,
                        float* __restrict__ Hin)
{
    int i = blockIdx.x*256 + threadIdx.x;   // (b*DI+d)*16+n, 32768 total
    int dn = i & 4095, b = i >> 12;
    float hv = 0.f;
    #pragma unroll
    for (int c=0;c<NCH;++c){
        int off = (b*NCH+c)*4096 + dn;
        Hin[off] = hv;
        hv = fmaf(Pb[off], hv, Qb[off]);
    }
}

// ---------------- pass 3 with fused dt-projection, emit y
__global__ __launch_bounds__(256) void k_scan3(
    const float* __restrict__ xm, const float* __restrict__ xdbl,
    const float* __restrict__ xz,
    const float* __restrict__ dtw, const float* __restrict__ dtbias,
    const float* __restrict__ A_log, const float* __restrict__ Dp,
    const float* __restrict__ Hin, float* __restrict__ yb)
{
    int g = threadIdx.x >> 4, n = threadIdx.x & 15;
    int gid = blockIdx.x*16 + g;
    int d = gid & (DI-1), c = (gid >> 8) & (NCH-1), b = gid >> 12;
    float An = -__expf(A_log[d*DSt + n]);
    float Dv = Dp[d];
    const float4 w0 = *reinterpret_cast<const float4*>(dtw + d*DTR);
    const float4 w1 = *reinterpret_cast<const float4*>(dtw + d*DTR + 4);
    const float bd = dtbias[d];
    int t0 = c*TC;
    const float* up  = xm  + (b*L2c + t0)*DI + d;
    const float* zp  = xz  + (b*L2c + t0)*2*DI + DI + d;
    const float* xrow = xdbl + (b*L2c + t0)*40;
    float* yp = yb + (b*L2c + t0)*DI + d;
    int srcbase = threadIdx.x & 0x30;
    float hv = Hin[gid*16+n];
    for (int jb=0; jb<TC; jb+=16){
        const float* xr = xrow + (jb+n)*40;
        float4 r0 = *reinterpret_cast<const float4*>(xr);
        float4 r1 = *reinterpret_cast<const float4*>(xr+4);
        float dtv = bd;
        dtv = fmaf(r0.x,w0.x, dtv); dtv = fmaf(r0.y,w0.y, dtv);
        dtv = fmaf(r0.z,w0.z, dtv); dtv = fmaf(r0.w,w0.w, dtv);
        dtv = fmaf(r1.x,w1.x, dtv); dtv = fmaf(r1.y,w1.y, dtv);
        dtv = fmaf(r1.z,w1.z, dtv); dtv = fmaf(r1.w,w1.w, dtv);
        dtv = softplusf_(dtv);
        #pragma unroll
        for (int jj=0; jj<16; ++jj){
            int j = jb + jj;
            float dtj = __shfl(dtv, srcbase + jj);
            float u  = up[j*DI];
            float Bv = xrow[j*40 + DTR + n];
            float Cv = xrow[j*40 + DTR + DSt + n];
            float dA = __expf(dtj*An);
            hv = fmaf(dA, hv, dtj*u*Bv);
            float p = hv*Cv;
            p += __shfl_xor(p,1); p += __shfl_xor(p,2);
            p += __shfl_xor(p,4); p += __shfl_xor(p,8);
            if (n == jj){
                float zv = zp[j*2*DI];
                yp[j*DI] = (p + u*Dv)*siluf_(zv);
            }
        }
    }
}

// ---------------- pool pass 1: partial mean over 64-token chunks
__global__ void k_pool1(const float* __restrict__ ln, float* __restrict__ partial)
{
    __shared__ float sbuf[256];
    int ch = blockIdx.x, b = blockIdx.y;
    int c = threadIdx.x & 127, half = threadIdx.x >> 7;
    int t0 = ch*(L2c/PCH);
    float s = 0.f;
    for (int j = half; j < L2c/PCH; j += 2)
        s += ln[(b*L2c + t0 + j)*DM + c];
    sbuf[threadIdx.x] = s;
    __syncthreads();
    if (half == 0)
        partial[(b*PCH + ch)*DM + c] = s + sbuf[threadIdx.x + 128];
}

// ---------------- pool pass 2
__global__ void k_pool2(const float* __restrict__ partial, float* __restrict__ pooled)
{
    int i = blockIdx.x*256 + threadIdx.x;   // b*128+c, 1024 total
    if (i >= Bc*DM) return;
    int b = i >> 7, c = i & 127;
    float s = 0.f;
    #pragma unroll
    for (int ch=0; ch<PCH; ++ch)
        s += partial[(b*PCH + ch)*DM + c];
    pooled[i] = s * (1.f/(float)L2c);
}

// ---------------- classifier
__global__ void k_cls(const float* __restrict__ pooled, const float* __restrict__ w,
                      const float* __restrict__ bias, float* __restrict__ out)
{
    int o = blockIdx.x*256 + threadIdx.x;
    if (o >= Bc*NC) return;
    int b = o/NC, n = o - b*NC;
    float s = bias[n];
    const float* pp = pooled + b*DM;
    const float* wp = w + n*DM;
    #pragma unroll 4
    for (int k=0;k<DM;++k) s = fmaf(pp[k], wp[k], s);
    out[o] = s;
}

extern "C" void kernel_launch(void* const* d_in, const int* in_sizes, int n_in,
                              void* d_out, int out_size, void* d_ws, size_t ws_size,
                              hipStream_t stream)
{
    const float* x        = (const float*)d_in[0];
    const float* conv0_w  = (const float*)d_in[1];
    const float* conv0_b  = (const float*)d_in[2];
    const float* bn0_g    = (const float*)d_in[3];
    const float* bn0_b    = (const float*)d_in[4];
    const float* conv1_w  = (const float*)d_in[5];
    const float* conv1_b  = (const float*)d_in[6];
    const float* bn1_g    = (const float*)d_in[7];
    const float* bn1_b    = (const float*)d_in[8];
    const float* ln_g     = (const float*)d_in[9];
    const float* ln_b     = (const float*)d_in[10];
    const float* in_proj_w= (const float*)d_in[11];
    const float* mconv_w  = (const float*)d_in[12];
    const float* mconv_b  = (const float*)d_in[13];
    const float* xproj_w  = (const float*)d_in[14];
    const float* dtproj_w = (const float*)d_in[15];
    const float* dtproj_b = (const float*)d_in[16];
    const float* A_log    = (const float*)d_in[17];
    const float* D_skip   = (const float*)d_in[18];
    const float* outproj_w= (const float*)d_in[19];
    const float* fnorm_g  = (const float*)d_in[20];
    const float* fnorm_b  = (const float*)d_in[21];
    const float* cls_w    = (const float*)d_in[22];
    const float* cls_b    = (const float*)d_in[23];
    float* out = (float*)d_out;

    float* ws = (float*)d_ws;
    float* sc0 = ws;        float* sh0 = ws+128;
    float* sc1 = ws+256;    float* sh1 = ws+384;
    float* h    = ws + 1024;              // 2,097,152
    float* ln   = h   + 2097152;          // 2,097,152
    float* xz   = ln  + 2097152;          // 8,388,608   (y0 aliases here)
    float* y0   = xz;
    float* xmc  = xz  + 8388608;          // 4,194,304   (y1 aliases here)
    float* y1   = xmc;
    float* xdbl = xmc + 4194304;          // 655,360
    float* yb   = xdbl + 655360 + 4194304; // (old dtb slot left unused)
    float* pooled = yb + 4194304;         // 1,024
    float* partial = pooled + 1024;       // 4,096

    // scan P/Q/Hin scratch aliases the ln buffer (dead during scan phase)
    float* Pb  = ln;
    float* Qb  = ln + 524288;
    float* Hin = ln + 1048576;

    // conv stage
    k_conv0<<<16384, 256, 0, stream>>>(x, conv0_w, conv0_b, y0);
    k_bnstats<<<128, 256, 0, stream>>>(y0, L1, bn0_g, bn0_b, sc0, sh0);
    k_conv1<<<dim3(L2c/32, Bc), 512, 0, stream>>>(y0, conv1_w, conv1_b, sc0, sh0, y1);
    k_bnstats<<<128, 256, 0, stream>>>(y1, L2c, bn1_g, bn1_b, sc1, sh1);
    k_bnt<<<dim3(4, 64, Bc), 256, 0, stream>>>(y1, sc1, sh1, h);

    for (int i=0;i<NL;++i){
        k_ln<<<4096, 256, 0, stream>>>(h, ln_g + i*DM, ln_b + i*DM, ln);
        k_gemm<false><<<dim3(128, 8), 256, 0, stream>>>(
            ln, DM, in_proj_w + i*512*DM, DM, xz, 512, 16384, 512, DM);
        k_dwconv<<<16384, 256, 0, stream>>>(xz, mconv_w + i*DI*4, mconv_b + i*DI, xmc);
        k_gemm<false><<<dim3(128, 1), 256, 0, stream>>>(
            xmc, DI, xproj_w + i*40*DI, DI, xdbl, 40, 16384, 40, DI);
        k_scan1<<<2048, 256, 0, stream>>>(xmc, xdbl,
            dtproj_w + i*DI*DTR, dtproj_b + i*DI, A_log + i*DI*DSt, Pb, Qb);
        k_scan2<<<128, 256, 0, stream>>>(Pb, Qb, Hin);
        k_scan3<<<2048, 256, 0, stream>>>(xmc, xdbl, xz,
            dtproj_w + i*DI*DTR, dtproj_b + i*DI,
            A_log + i*DI*DSt, D_skip + i*DI, Hin, yb);
        k_gemm<true><<<dim3(128, 2), 256, 0, stream>>>(
            yb, DI, outproj_w + i*DM*DI, DI, h, DM, 16384, DM, DI);
    }

    k_ln<<<4096, 256, 0, stream>>>(h, fnorm_g, fnorm_b, ln);
    k_pool1<<<dim3(PCH, Bc), 256, 0, stream>>>(ln, partial);
    k_pool2<<<4, 256, 0, stream>>>(partial, pooled);
    k_cls<<<4, 256, 0, stream>>>(pooled, cls_w, cls_b, out);
}

// Round 10
// 1451.313 us; speedup vs baseline: 2.3353x; 1.0840x over previous
//
#include <hip/hip_runtime.h>
#include <hip/hip_bf16.h>

#define DEV __device__ __forceinline__

static constexpr int Bc = 8;
static constexpr int L0 = 8192, L1 = 4096, L2c = 2048;
static constexpr int DM = 128, DI = 256, DSt = 16, DTR = 8, NL = 4, NC = 100;
static constexpr int KC = 9;
static constexpr int TC = 128, NCH = 16;   // scan chunking
static constexpr int PCH = 32;             // pool chunking

DEV float sigmoidf_(float x){ return 1.f/(1.f+__expf(-x)); }
DEV float siluf_(float x){ return x*sigmoidf_(x); }
DEV float softplusf_(float x){ return (x>20.f)? x : log1pf(__expf(x)); }

// ---------------- conv0: x(8,4,8192) -> y0(8,128,4096), stride2 pad4, relu
__global__ void k_conv0(const float* __restrict__ x, const float* __restrict__ w,
                        const float* __restrict__ bias, float* __restrict__ y)
{
    int o = blockIdx.x*256 + threadIdx.x;           // (b*128+co)*4096 + t
    int t  = o & (L1-1);
    int co = (o >> 12) & (DM-1);
    int b  = o >> 19;
    const float* wp = w + co*4*KC;
    float acc = bias[co];
    int base = 2*t - 4;
    #pragma unroll
    for (int ci=0; ci<4; ++ci){
        const float* xp = x + (b*4+ci)*L0;
        #pragma unroll
        for (int k=0;k<KC;++k){
            int tt = base + k;
            if (tt >= 0 && tt < L0) acc = fmaf(wp[ci*KC+k], xp[tt], acc);
        }
    }
    y[o] = fmaxf(acc, 0.f);
}

// ---------------- BN stats pass 1: partial sums over 16 chunks per channel
__global__ void k_bns1(const float* __restrict__ y, int Lc,
                       float* __restrict__ ps, float* __restrict__ pq)
{
    int ch = blockIdx.x, c = blockIdx.y;
    int Ntot = Bc*Lc, CH = Ntot/16;
    int i0 = ch*CH;
    float s=0.f, sq=0.f;
    for (int i=i0+threadIdx.x; i<i0+CH; i+=256){
        int b = i / Lc, t = i - b*Lc;
        float v = y[(b*DM+c)*Lc + t];
        s += v; sq = fmaf(v, v, sq);
    }
    #pragma unroll
    for (int off=32; off; off>>=1){ s += __shfl_down(s, off); sq += __shfl_down(sq, off); }
    __shared__ float rs[4], rq[4];
    int wid = threadIdx.x>>6, lane = threadIdx.x&63;
    if (lane==0){ rs[wid]=s; rq[wid]=sq; }
    __syncthreads();
    if (threadIdx.x==0){
        ps[c*16+ch] = rs[0]+rs[1]+rs[2]+rs[3];
        pq[c*16+ch] = rq[0]+rq[1]+rq[2]+rq[3];
    }
}

// ---------------- BN stats pass 2: reduce partials -> scale/shift
__global__ void k_bns2(const float* __restrict__ ps, const float* __restrict__ pq,
                       int Lc, const float* __restrict__ g, const float* __restrict__ bta,
                       float* __restrict__ scale, float* __restrict__ shift)
{
    int c = threadIdx.x;
    if (c >= DM) return;
    float S=0.f, Q=0.f;
    #pragma unroll
    for (int ch=0; ch<16; ++ch){ S += ps[c*16+ch]; Q += pq[c*16+ch]; }
    float inv = 1.f/(float)(Bc*Lc);
    float mu = S*inv;
    float var = Q*inv - mu*mu;
    float sc = g[c]*rsqrtf(var + 1e-5f);
    scale[c]=sc; shift[c]=bta[c]-mu*sc;
}

// ---------------- weight transpose for conv1: [co][ci][k] -> [ci][k][co]
__global__ void k_wt(const float* __restrict__ w, float* __restrict__ wt)
{
    int i = blockIdx.x*256 + threadIdx.x;     // i = (ci*9+k)*128+co
    if (i >= DM*DM*KC) return;
    int co = i & 127;
    int cik = i >> 7;
    wt[i] = w[co*DM*KC + cik];
}

// ---------------- conv1: 256 threads = 128co x 2 t-halves, 16 outputs each
// weights read coalesced from transposed wt[ci][k][co]
__global__ __launch_bounds__(256) void k_conv1(
    const float* __restrict__ y0, const float* __restrict__ wt,
    const float* __restrict__ bias,
    const float* __restrict__ sc0, const float* __restrict__ sh0,
    float* __restrict__ y1)
{
    __shared__ __align__(16) float in_s[DM][76];
    int b  = blockIdx.y;
    int t0 = blockIdx.x * 32;
    for (int idx=threadIdx.x; idx < DM*71; idx += 256){
        int ci = idx / 71, j = idx - ci*71;
        int tt = 2*t0 - 4 + j;
        float v = 0.f;
        if (tt >= 0 && tt < L1) v = fmaf(y0[(b*DM+ci)*L1 + tt], sc0[ci], sh0[ci]);
        in_s[ci][j] = v;
    }
    __syncthreads();
    int co = threadIdx.x & 127;
    int th = threadIdx.x >> 7;       // t-half: 0/1
    float acc[16];
    #pragma unroll
    for (int j=0;j<16;++j) acc[j]=bias[co];
    const int jbase = th*16;
    const float* wtp = wt + co;
    for (int ci=0; ci<DM; ++ci){
        float wv[KC];
        #pragma unroll
        for (int k=0;k<KC;++k) wv[k] = wtp[(ci*KC+k)*DM];
        const float4* rowp = reinterpret_cast<const float4*>(&in_s[ci][2*jbase]);
        float win[44];
        #pragma unroll
        for (int q=0;q<11;++q){
            float4 v4 = rowp[q];
            win[4*q]=v4.x; win[4*q+1]=v4.y; win[4*q+2]=v4.z; win[4*q+3]=v4.w;
        }
        #pragma unroll
        for (int j=0;j<16;++j)
            #pragma unroll
            for (int k=0;k<KC;++k)
                acc[j] = fmaf(wv[k], win[2*j+k], acc[j]);
    }
    #pragma unroll
    for (int j=0;j<16;++j){
        int t = t0 + jbase + j;
        y1[(b*DM+co)*L2c + t] = fmaxf(acc[j], 0.f);
    }
}

// ---------------- BN apply + transpose: y1(8,128,2048) -> h(8,2048,128)
__global__ void k_bnt(const float* __restrict__ y1, const float* __restrict__ sc,
                      const float* __restrict__ sh, float* __restrict__ h)
{
    __shared__ float tile[32][33];
    int b  = blockIdx.z;
    int c0 = blockIdx.x * 32;
    int t0 = blockIdx.y * 32;
    int tx = threadIdx.x & 31, ty = threadIdx.x >> 5;   // 8 rows
    for (int i=ty; i<32; i+=8)
        tile[i][tx] = fmaf(y1[(b*DM + c0+i)*L2c + t0+tx], sc[c0+i], sh[c0+i]);
    __syncthreads();
    for (int i=ty; i<32; i+=8)
        h[(b*L2c + t0+i)*DM + c0+tx] = tile[tx][i];
}

// ---------------- LayerNorm over D=128, one wave per token
__global__ void k_ln(const float* __restrict__ h, const float* __restrict__ g,
                     const float* __restrict__ bta, float* __restrict__ out)
{
    int tok  = blockIdx.x*4 + (threadIdx.x>>6);
    int lane = threadIdx.x & 63;
    const float2 v = reinterpret_cast<const float2*>(h + tok*DM)[lane];
    float s = v.x + v.y;
    #pragma unroll
    for (int off=32; off; off>>=1) s += __shfl_xor(s, off);
    float mu = s * (1.f/DM);
    float dx = v.x-mu, dy = v.y-mu;
    float q = dx*dx + dy*dy;
    #pragma unroll
    for (int off=32; off; off>>=1) q += __shfl_xor(q, off);
    float rstd = rsqrtf(q*(1.f/DM) + 1e-5f);
    float2 gg = reinterpret_cast<const float2*>(g)[lane];
    float2 bb = reinterpret_cast<const float2*>(bta)[lane];
    float2 o;
    o.x = fmaf(dx*rstd, gg.x, bb.x);
    o.y = fmaf(dy*rstd, gg.y, bb.y);
    reinterpret_cast<float2*>(out + tok*DM)[lane] = o;
}

// ---------------- fp32 GEMM: C[M,N] (+)= A[M,K] @ W[N,K]^T
// BM=128, BN=64, BK=16, 256 threads, 8x4 microtile. K must be multiple of 16.
template<bool ACC>
__global__ __launch_bounds__(256) void k_gemm(
    const float* __restrict__ A, int lda,
    const float* __restrict__ W, int ldw,
    float* __restrict__ C, int ldc,
    int M, int N, int K)
{
    __shared__ __align__(16) float As[16][132];
    __shared__ __align__(16) float Ws[16][68];
    int m0 = blockIdx.x*128, n0 = blockIdx.y*64;
    int tx = threadIdx.x & 15, ty = threadIdx.x >> 4;
    float acc[8][4] = {};
    for (int k0 = 0; k0 < K; k0 += 16){
        __syncthreads();
        {
            int ra = threadIdx.x >> 1;
            int ca = (threadIdx.x & 1) * 8;
            const float* ap = A + (m0+ra)*lda + k0 + ca;
            #pragma unroll
            for (int q=0;q<8;++q) As[ca+q][ra] = ap[q];
            int rw = threadIdx.x >> 2;
            int cw = (threadIdx.x & 3) * 4;
            const float* wp2 = W + (n0+rw)*ldw + k0 + cw;
            bool nok = (n0 + rw) < N;
            #pragma unroll
            for (int q=0;q<4;++q) Ws[cw+q][rw] = nok ? wp2[q] : 0.f;
        }
        __syncthreads();
        #pragma unroll
        for (int kk=0; kk<16; ++kk){
            float4 a0 = *reinterpret_cast<const float4*>(&As[kk][ty*8]);
            float4 a1 = *reinterpret_cast<const float4*>(&As[kk][ty*8+4]);
            float4 w4 = *reinterpret_cast<const float4*>(&Ws[kk][tx*4]);
            float av[8] = {a0.x,a0.y,a0.z,a0.w,a1.x,a1.y,a1.z,a1.w};
            float wv[4] = {w4.x,w4.y,w4.z,w4.w};
            #pragma unroll
            for (int i=0;i<8;++i)
                #pragma unroll
                for (int j=0;j<4;++j)
                    acc[i][j] = fmaf(av[i], wv[j], acc[i][j]);
        }
    }
    #pragma unroll
    for (int i=0;i<8;++i){
        int m = m0 + ty*8 + i;
        #pragma unroll
        for (int j=0;j<4;++j){
            int n = n0 + tx*4 + j;
            if (n < N){
                float* cp = C + m*ldc + n;
                if (ACC) *cp += acc[i][j]; else *cp = acc[i][j];
            }
        }
    }
}

// ---------------- depthwise causal conv (k=4) + bias + silu, from xz[:, :, :256]
__global__ void k_dwconv(const float* __restrict__ xz, const float* __restrict__ w,
                         const float* __restrict__ bias, float* __restrict__ xmc)
{
    int o = blockIdx.x*256 + threadIdx.x;   // (b*2048+t)*256 + d
    int d = o & 255, t = (o>>8) & 2047, b = o >> 19;
    float acc = bias[d];
    #pragma unroll
    for (int k=0;k<4;++k){
        int tt = t - 3 + k;
        if (tt >= 0) acc = fmaf(w[d*4+k], xz[(b*L2c+tt)*512 + d], acc);
    }
    xmc[o] = siluf_(acc);
}

// ---------------- scan pass 1 with fused dt-projection.
__global__ __launch_bounds__(256) void k_scan1(
    const float* __restrict__ xm, const float* __restrict__ xdbl,
    const float* __restrict__ dtw, const float* __restrict__ dtbias,
    const float* __restrict__ A_log,
    float* __restrict__ Pb, float* __restrict__ Qb)
{
    int g = threadIdx.x >> 4, n = threadIdx.x & 15;
    int gid = blockIdx.x*16 + g;
    int d = gid & (DI-1), c = (gid >> 8) & (NCH-1), b = gid >> 12;
    float An = -__expf(A_log[d*DSt + n]);
    const float4 w0 = *reinterpret_cast<const float4*>(dtw + d*DTR);
    const float4 w1 = *reinterpret_cast<const float4*>(dtw + d*DTR + 4);
    const float bd = dtbias[d];
    int t0 = c*TC;
    const float* up  = xm  + (b*L2c + t0)*DI + d;
    const float* xrow = xdbl + (b*L2c + t0)*40;
    int srcbase = threadIdx.x & 0x30;   // group base lane within wave
    float P = 1.f, Q = 0.f;
    for (int jb=0; jb<TC; jb+=16){
        const float* xr = xrow + (jb+n)*40;
        float4 r0 = *reinterpret_cast<const float4*>(xr);
        float4 r1 = *reinterpret_cast<const float4*>(xr+4);
        float dtv = bd;
        dtv = fmaf(r0.x,w0.x, dtv); dtv = fmaf(r0.y,w0.y, dtv);
        dtv = fmaf(r0.z,w0.z, dtv); dtv = fmaf(r0.w,w0.w, dtv);
        dtv = fmaf(r1.x,w1.x, dtv); dtv = fmaf(r1.y,w1.y, dtv);
        dtv = fmaf(r1.z,w1.z, dtv); dtv = fmaf(r1.w,w1.w, dtv);
        dtv = softplusf_(dtv);
        #pragma unroll
        for (int jj=0; jj<16; ++jj){
            float dtj = __shfl(dtv, srcbase + jj);
            float u  = up[(jb+jj)*DI];
            float Bv = xrow[(jb+jj)*40 + DTR + n];
            float dA = __expf(dtj*An);
            P *= dA;
            Q = fmaf(dA, Q, dtj*u*Bv);
        }
    }
    Pb[gid*16+n] = P;
    Qb[gid*16+n] = Q;
}

// ---------------- pass 2 (stitch)
__global__ void k_scan2(const float* __restrict__ Pb, const float* __restrict__ Qb,
                        float* __restrict__ Hin)
{
    int i = blockIdx.x*256 + threadIdx.x;   // (b*DI+d)*16+n, 32768 total
    int dn = i & 4095, b = i >> 12;
    float hv = 0.f;
    #pragma unroll
    for (int c=0;c<NCH;++c){
        int off = (b*NCH+c)*4096 + dn;
        Hin[off] = hv;
        hv = fmaf(Pb[off], hv, Qb[off]);
    }
}

// ---------------- pass 3 with fused dt-projection, emit y
__global__ __launch_bounds__(256) void k_scan3(
    const float* __restrict__ xm, const float* __restrict__ xdbl,
    const float* __restrict__ xz,
    const float* __restrict__ dtw, const float* __restrict__ dtbias,
    const float* __restrict__ A_log, const float* __restrict__ Dp,
    const float* __restrict__ Hin, float* __restrict__ yb)
{
    int g = threadIdx.x >> 4, n = threadIdx.x & 15;
    int gid = blockIdx.x*16 + g;
    int d = gid & (DI-1), c = (gid >> 8) & (NCH-1), b = gid >> 12;
    float An = -__expf(A_log[d*DSt + n]);
    float Dv = Dp[d];
    const float4 w0 = *reinterpret_cast<const float4*>(dtw + d*DTR);
    const float4 w1 = *reinterpret_cast<const float4*>(dtw + d*DTR + 4);
    const float bd = dtbias[d];
    int t0 = c*TC;
    const float* up  = xm  + (b*L2c + t0)*DI + d;
    const float* zp  = xz  + (b*L2c + t0)*2*DI + DI + d;
    const float* xrow = xdbl + (b*L2c + t0)*40;
    float* yp = yb + (b*L2c + t0)*DI + d;
    int srcbase = threadIdx.x & 0x30;
    float hv = Hin[gid*16+n];
    for (int jb=0; jb<TC; jb+=16){
        const float* xr = xrow + (jb+n)*40;
        float4 r0 = *reinterpret_cast<const float4*>(xr);
        float4 r1 = *reinterpret_cast<const float4*>(xr+4);
        float dtv = bd;
        dtv = fmaf(r0.x,w0.x, dtv); dtv = fmaf(r0.y,w0.y, dtv);
        dtv = fmaf(r0.z,w0.z, dtv); dtv = fmaf(r0.w,w0.w, dtv);
        dtv = fmaf(r1.x,w1.x, dtv); dtv = fmaf(r1.y,w1.y, dtv);
        dtv = fmaf(r1.z,w1.z, dtv); dtv = fmaf(r1.w,w1.w, dtv);
        dtv = softplusf_(dtv);
        #pragma unroll
        for (int jj=0; jj<16; ++jj){
            int j = jb + jj;
            float dtj = __shfl(dtv, srcbase + jj);
            float u  = up[j*DI];
            float Bv = xrow[j*40 + DTR + n];
            float Cv = xrow[j*40 + DTR + DSt + n];
            float dA = __expf(dtj*An);
            hv = fmaf(dA, hv, dtj*u*Bv);
            float p = hv*Cv;
            p += __shfl_xor(p,1); p += __shfl_xor(p,2);
            p += __shfl_xor(p,4); p += __shfl_xor(p,8);
            if (n == jj){
                float zv = zp[j*2*DI];
                yp[j*DI] = (p + u*Dv)*siluf_(zv);
            }
        }
    }
}

// ---------------- pool pass 1: partial mean over 64-token chunks
__global__ void k_pool1(const float* __restrict__ ln, float* __restrict__ partial)
{
    __shared__ float sbuf[256];
    int ch = blockIdx.x, b = blockIdx.y;
    int c = threadIdx.x & 127, half = threadIdx.x >> 7;
    int t0 = ch*(L2c/PCH);
    float s = 0.f;
    for (int j = half; j < L2c/PCH; j += 2)
        s += ln[(b*L2c + t0 + j)*DM + c];
    sbuf[threadIdx.x] = s;
    __syncthreads();
    if (half == 0)
        partial[(b*PCH + ch)*DM + c] = s + sbuf[threadIdx.x + 128];
}

// ---------------- pool pass 2
__global__ void k_pool2(const float* __restrict__ partial, float* __restrict__ pooled)
{
    int i = blockIdx.x*256 + threadIdx.x;   // b*128+c, 1024 total
    if (i >= Bc*DM) return;
    int b = i >> 7, c = i & 127;
    float s = 0.f;
    #pragma unroll
    for (int ch=0; ch<PCH; ++ch)
        s += partial[(b*PCH + ch)*DM + c];
    pooled[i] = s * (1.f/(float)L2c);
}

// ---------------- classifier
__global__ void k_cls(const float* __restrict__ pooled, const float* __restrict__ w,
                      const float* __restrict__ bias, float* __restrict__ out)
{
    int o = blockIdx.x*256 + threadIdx.x;
    if (o >= Bc*NC) return;
    int b = o/NC, n = o - b*NC;
    float s = bias[n];
    const float* pp = pooled + b*DM;
    const float* wp = w + n*DM;
    #pragma unroll 4
    for (int k=0;k<DM;++k) s = fmaf(pp[k], wp[k], s);
    out[o] = s;
}

extern "C" void kernel_launch(void* const* d_in, const int* in_sizes, int n_in,
                              void* d_out, int out_size, void* d_ws, size_t ws_size,
                              hipStream_t stream)
{
    const float* x        = (const float*)d_in[0];
    const float* conv0_w  = (const float*)d_in[1];
    const float* conv0_b  = (const float*)d_in[2];
    const float* bn0_g    = (const float*)d_in[3];
    const float* bn0_b    = (const float*)d_in[4];
    const float* conv1_w  = (const float*)d_in[5];
    const float* conv1_b  = (const float*)d_in[6];
    const float* bn1_g    = (const float*)d_in[7];
    const float* bn1_b    = (const float*)d_in[8];
    const float* ln_g     = (const float*)d_in[9];
    const float* ln_b     = (const float*)d_in[10];
    const float* in_proj_w= (const float*)d_in[11];
    const float* mconv_w  = (const float*)d_in[12];
    const float* mconv_b  = (const float*)d_in[13];
    const float* xproj_w  = (const float*)d_in[14];
    const float* dtproj_w = (const float*)d_in[15];
    const float* dtproj_b = (const float*)d_in[16];
    const float* A_log    = (const float*)d_in[17];
    const float* D_skip   = (const float*)d_in[18];
    const float* outproj_w= (const float*)d_in[19];
    const float* fnorm_g  = (const float*)d_in[20];
    const float* fnorm_b  = (const float*)d_in[21];
    const float* cls_w    = (const float*)d_in[22];
    const float* cls_b    = (const float*)d_in[23];
    float* out = (float*)d_out;

    float* ws = (float*)d_ws;
    float* sc0 = ws;        float* sh0 = ws+128;
    float* sc1 = ws+256;    float* sh1 = ws+384;
    float* h    = ws + 1024;              // 2,097,152
    float* ln   = h   + 2097152;          // 2,097,152
    float* xz   = ln  + 2097152;          // 8,388,608   (y0 aliases here)
    float* y0   = xz;
    float* xmc  = xz  + 8388608;          // 4,194,304   (y1 aliases here)
    float* y1   = xmc;
    float* xdbl = xmc + 4194304;          // 655,360
    float* wt   = xdbl + 655360;          // 147,456 (in old dtb hole)
    float* yb   = xdbl + 655360 + 4194304;
    float* pooled = yb + 4194304;         // 1,024
    float* partial = pooled + 1024;       // 4,096
    float* bns_s  = partial + 4096;       // 2,048
    float* bns_q  = bns_s + 2048;         // 2,048

    // scan P/Q/Hin scratch aliases the ln buffer (dead during scan phase)
    float* Pb  = ln;
    float* Qb  = ln + 524288;
    float* Hin = ln + 1048576;

    // conv stage
    k_wt<<<576, 256, 0, stream>>>(conv1_w, wt);
    k_conv0<<<16384, 256, 0, stream>>>(x, conv0_w, conv0_b, y0);
    k_bns1<<<dim3(16, DM), 256, 0, stream>>>(y0, L1, bns_s, bns_q);
    k_bns2<<<1, 128, 0, stream>>>(bns_s, bns_q, L1, bn0_g, bn0_b, sc0, sh0);
    k_conv1<<<dim3(L2c/32, Bc), 256, 0, stream>>>(y0, wt, conv1_b, sc0, sh0, y1);
    k_bns1<<<dim3(16, DM), 256, 0, stream>>>(y1, L2c, bns_s, bns_q);
    k_bns2<<<1, 128, 0, stream>>>(bns_s, bns_q, L2c, bn1_g, bn1_b, sc1, sh1);
    k_bnt<<<dim3(4, 64, Bc), 256, 0, stream>>>(y1, sc1, sh1, h);

    for (int i=0;i<NL;++i){
        k_ln<<<4096, 256, 0, stream>>>(h, ln_g + i*DM, ln_b + i*DM, ln);
        k_gemm<false><<<dim3(128, 8), 256, 0, stream>>>(
            ln, DM, in_proj_w + i*512*DM, DM, xz, 512, 16384, 512, DM);
        k_dwconv<<<16384, 256, 0, stream>>>(xz, mconv_w + i*DI*4, mconv_b + i*DI, xmc);
        k_gemm<false><<<dim3(128, 1), 256, 0, stream>>>(
            xmc, DI, xproj_w + i*40*DI, DI, xdbl, 40, 16384, 40, DI);
        k_scan1<<<2048, 256, 0, stream>>>(xmc, xdbl,
            dtproj_w + i*DI*DTR, dtproj_b + i*DI, A_log + i*DI*DSt, Pb, Qb);
        k_scan2<<<128, 256, 0, stream>>>(Pb, Qb, Hin);
        k_scan3<<<2048, 256, 0, stream>>>(xmc, xdbl, xz,
            dtproj_w + i*DI*DTR, dtproj_b + i*DI,
            A_log + i*DI*DSt, D_skip + i*DI, Hin, yb);
        k_gemm<true><<<dim3(128, 2), 256, 0, stream>>>(
            yb, DI, outproj_w + i*DM*DI, DI, h, DM, 16384, DM, DI);
    }

    k_ln<<<4096, 256, 0, stream>>>(h, fnorm_g, fnorm_b, ln);
    k_pool1<<<dim3(PCH, Bc), 256, 0, stream>>>(ln, partial);
    k_pool2<<<4, 256, 0, stream>>>(partial, pooled);
    k_cls<<<4, 256, 0, stream>>>(pooled, cls_w, cls_b, out);
}

// Round 12
// 1209.499 us; speedup vs baseline: 2.8021x; 1.1999x over previous
//
#include <hip/hip_runtime.h>
#include <hip/hip_bf16.h>

#define DEV __device__ __forceinline__

static constexpr int Bc = 8;
static constexpr int L0 = 8192, L1 = 4096, L2c = 2048;
static constexpr int DM = 128, DI = 256, DSt = 16, DTR = 8, NL = 4, NC = 100;
static constexpr int KC = 9;
static constexpr int TC = 128, NCH = 16;   // scan chunking
static constexpr int PCH = 32;             // pool chunking

DEV float sigmoidf_(float x){ return 1.f/(1.f+__expf(-x)); }
DEV float siluf_(float x){ return x*sigmoidf_(x); }
DEV float softplusf_(float x){ return (x>20.f)? x : log1pf(__expf(x)); }

// ---------------- conv0: x(8,4,8192) -> y0(8,128,4096), stride2 pad4, relu
__global__ void k_conv0(const float* __restrict__ x, const float* __restrict__ w,
                        const float* __restrict__ bias, float* __restrict__ y)
{
    int o = blockIdx.x*256 + threadIdx.x;           // (b*128+co)*4096 + t
    int t  = o & (L1-1);
    int co = (o >> 12) & (DM-1);
    int b  = o >> 19;
    const float* wp = w + co*4*KC;
    float acc = bias[co];
    int base = 2*t - 4;
    #pragma unroll
    for (int ci=0; ci<4; ++ci){
        const float* xp = x + (b*4+ci)*L0;
        #pragma unroll
        for (int k=0;k<KC;++k){
            int tt = base + k;
            if (tt >= 0 && tt < L0) acc = fmaf(wp[ci*KC+k], xp[tt], acc);
        }
    }
    y[o] = fmaxf(acc, 0.f);
}

// ---------------- BN stats pass 1: partial sums over 16 chunks per channel
__global__ void k_bns1(const float* __restrict__ y, int Lc,
                       float* __restrict__ ps, float* __restrict__ pq)
{
    int ch = blockIdx.x, c = blockIdx.y;
    int Ntot = Bc*Lc, CH = Ntot/16;
    int i0 = ch*CH;
    float s=0.f, sq=0.f;
    for (int i=i0+threadIdx.x; i<i0+CH; i+=256){
        int b = i / Lc, t = i - b*Lc;
        float v = y[(b*DM+c)*Lc + t];
        s += v; sq = fmaf(v, v, sq);
    }
    #pragma unroll
    for (int off=32; off; off>>=1){ s += __shfl_down(s, off); sq += __shfl_down(sq, off); }
    __shared__ float rs[4], rq[4];
    int wid = threadIdx.x>>6, lane = threadIdx.x&63;
    if (lane==0){ rs[wid]=s; rq[wid]=sq; }
    __syncthreads();
    if (threadIdx.x==0){
        ps[c*16+ch] = rs[0]+rs[1]+rs[2]+rs[3];
        pq[c*16+ch] = rq[0]+rq[1]+rq[2]+rq[3];
    }
}

// ---------------- BN stats pass 2: reduce partials -> scale/shift
__global__ void k_bns2(const float* __restrict__ ps, const float* __restrict__ pq,
                       int Lc, const float* __restrict__ g, const float* __restrict__ bta,
                       float* __restrict__ scale, float* __restrict__ shift)
{
    int c = threadIdx.x;
    if (c >= DM) return;
    float S=0.f, Q=0.f;
    #pragma unroll
    for (int ch=0; ch<16; ++ch){ S += ps[c*16+ch]; Q += pq[c*16+ch]; }
    float inv = 1.f/(float)(Bc*Lc);
    float mu = S*inv;
    float var = Q*inv - mu*mu;
    float sc = g[c]*rsqrtf(var + 1e-5f);
    scale[c]=sc; shift[c]=bta[c]-mu*sc;
}

// ---------------- weight transpose for conv1: [co][ci][k] -> [ci][k][co]
__global__ void k_wt(const float* __restrict__ w, float* __restrict__ wt)
{
    int i = blockIdx.x*256 + threadIdx.x;     // i = (ci*9+k)*128+co
    if (i >= DM*DM*KC) return;
    int co = i & 127;
    int cik = i >> 7;
    wt[i] = w[co*DM*KC + cik];
}

// ---------------- conv1: 256 threads = 128co x 2 t-halves, 16 outputs each
// weights read coalesced from transposed wt[ci][k][co]
__global__ __launch_bounds__(256) void k_conv1(
    const float* __restrict__ y0, const float* __restrict__ wt,
    const float* __restrict__ bias,
    const float* __restrict__ sc0, const float* __restrict__ sh0,
    float* __restrict__ y1)
{
    __shared__ __align__(16) float in_s[DM][76];
    int b  = blockIdx.y;
    int t0 = blockIdx.x * 32;
    for (int idx=threadIdx.x; idx < DM*71; idx += 256){
        int ci = idx / 71, j = idx - ci*71;
        int tt = 2*t0 - 4 + j;
        float v = 0.f;
        if (tt >= 0 && tt < L1) v = fmaf(y0[(b*DM+ci)*L1 + tt], sc0[ci], sh0[ci]);
        in_s[ci][j] = v;
    }
    __syncthreads();
    int co = threadIdx.x & 127;
    int th = threadIdx.x >> 7;       // t-half: 0/1
    float acc[16];
    #pragma unroll
    for (int j=0;j<16;++j) acc[j]=bias[co];
    const int jbase = th*16;
    const float* wtp = wt + co;
    for (int ci=0; ci<DM; ++ci){
        float wv[KC];
        #pragma unroll
        for (int k=0;k<KC;++k) wv[k] = wtp[(ci*KC+k)*DM];
        const float4* rowp = reinterpret_cast<const float4*>(&in_s[ci][2*jbase]);
        float win[44];
        #pragma unroll
        for (int q=0;q<11;++q){
            float4 v4 = rowp[q];
            win[4*q]=v4.x; win[4*q+1]=v4.y; win[4*q+2]=v4.z; win[4*q+3]=v4.w;
        }
        #pragma unroll
        for (int j=0;j<16;++j)
            #pragma unroll
            for (int k=0;k<KC;++k)
                acc[j] = fmaf(wv[k], win[2*j+k], acc[j]);
    }
    #pragma unroll
    for (int j=0;j<16;++j){
        int t = t0 + jbase + j;
        y1[(b*DM+co)*L2c + t] = fmaxf(acc[j], 0.f);
    }
}

// ---------------- BN apply + transpose: y1(8,128,2048) -> h(8,2048,128)
__global__ void k_bnt(const float* __restrict__ y1, const float* __restrict__ sc,
                      const float* __restrict__ sh, float* __restrict__ h)
{
    __shared__ float tile[32][33];
    int b  = blockIdx.z;
    int c0 = blockIdx.x * 32;
    int t0 = blockIdx.y * 32;
    int tx = threadIdx.x & 31, ty = threadIdx.x >> 5;   // 8 rows
    for (int i=ty; i<32; i+=8)
        tile[i][tx] = fmaf(y1[(b*DM + c0+i)*L2c + t0+tx], sc[c0+i], sh[c0+i]);
    __syncthreads();
    for (int i=ty; i<32; i+=8)
        h[(b*L2c + t0+i)*DM + c0+tx] = tile[tx][i];
}

// ---------------- LayerNorm over D=128, one wave per token
__global__ void k_ln(const float* __restrict__ h, const float* __restrict__ g,
                     const float* __restrict__ bta, float* __restrict__ out)
{
    int tok  = blockIdx.x*4 + (threadIdx.x>>6);
    int lane = threadIdx.x & 63;
    const float2 v = reinterpret_cast<const float2*>(h + tok*DM)[lane];
    float s = v.x + v.y;
    #pragma unroll
    for (int off=32; off; off>>=1) s += __shfl_xor(s, off);
    float mu = s * (1.f/DM);
    float dx = v.x-mu, dy = v.y-mu;
    float q = dx*dx + dy*dy;
    #pragma unroll
    for (int off=32; off; off>>=1) q += __shfl_xor(q, off);
    float rstd = rsqrtf(q*(1.f/DM) + 1e-5f);
    float2 gg = reinterpret_cast<const float2*>(g)[lane];
    float2 bb = reinterpret_cast<const float2*>(bta)[lane];
    float2 o;
    o.x = fmaf(dx*rstd, gg.x, bb.x);
    o.y = fmaf(dy*rstd, gg.y, bb.y);
    reinterpret_cast<float2*>(out + tok*DM)[lane] = o;
}

// ---------------- fp32 GEMM: C[M,N] (+)= A[M,K] @ W[N,K]^T
// BM=128, BN=64, BK=16, 256 threads, 8x4 microtile. K must be multiple of 16.
template<bool ACC>
__global__ __launch_bounds__(256) void k_gemm(
    const float* __restrict__ A, int lda,
    const float* __restrict__ W, int ldw,
    float* __restrict__ C, int ldc,
    int M, int N, int K)
{
    __shared__ __align__(16) float As[16][132];
    __shared__ __align__(16) float Ws[16][68];
    int m0 = blockIdx.x*128, n0 = blockIdx.y*64;
    int tx = threadIdx.x & 15, ty = threadIdx.x >> 4;
    float acc[8][4] = {};
    for (int k0 = 0; k0 < K; k0 += 16){
        __syncthreads();
        {
            int ra = threadIdx.x >> 1;
            int ca = (threadIdx.x & 1) * 8;
            const float* ap = A + (m0+ra)*lda + k0 + ca;
            #pragma unroll
            for (int q=0;q<8;++q) As[ca+q][ra] = ap[q];
            int rw = threadIdx.x >> 2;
            int cw = (threadIdx.x & 3) * 4;
            const float* wp2 = W + (n0+rw)*ldw + k0 + cw;
            bool nok = (n0 + rw) < N;
            #pragma unroll
            for (int q=0;q<4;++q) Ws[cw+q][rw] = nok ? wp2[q] : 0.f;
        }
        __syncthreads();
        #pragma unroll
        for (int kk=0; kk<16; ++kk){
            float4 a0 = *reinterpret_cast<const float4*>(&As[kk][ty*8]);
            float4 a1 = *reinterpret_cast<const float4*>(&As[kk][ty*8+4]);
            float4 w4 = *reinterpret_cast<const float4*>(&Ws[kk][tx*4]);
            float av[8] = {a0.x,a0.y,a0.z,a0.w,a1.x,a1.y,a1.z,a1.w};
            float wv[4] = {w4.x,w4.y,w4.z,w4.w};
            #pragma unroll
            for (int i=0;i<8;++i)
                #pragma unroll
                for (int j=0;j<4;++j)
                    acc[i][j] = fmaf(av[i], wv[j], acc[i][j]);
        }
    }
    #pragma unroll
    for (int i=0;i<8;++i){
        int m = m0 + ty*8 + i;
        #pragma unroll
        for (int j=0;j<4;++j){
            int n = n0 + tx*4 + j;
            if (n < N){
                float* cp = C + m*ldc + n;
                if (ACC) *cp += acc[i][j]; else *cp = acc[i][j];
            }
        }
    }
}

// ---------------- depthwise causal conv (k=4) + bias + silu, from xz[:, :, :256]
__global__ void k_dwconv(const float* __restrict__ xz, const float* __restrict__ w,
                         const float* __restrict__ bias, float* __restrict__ xmc)
{
    int o = blockIdx.x*256 + threadIdx.x;   // (b*2048+t)*256 + d
    int d = o & 255, t = (o>>8) & 2047, b = o >> 19;
    float acc = bias[d];
    #pragma unroll
    for (int k=0;k<4;++k){
        int tt = t - 3 + k;
        if (tt >= 0) acc = fmaf(w[d*4+k], xz[(b*L2c+tt)*512 + d], acc);
    }
    xmc[o] = siluf_(acc);
}

// ---------------- scan pass 1 with fused dt-projection.
__global__ __launch_bounds__(256) void k_scan1(
    const float* __restrict__ xm, const float* __restrict__ xdbl,
    const float* __restrict__ dtw, const float* __restrict__ dtbias,
    const float* __restrict__ A_log,
    float* __restrict__ Pb, float* __restrict__ Qb)
{
    int g = threadIdx.x >> 4, n = threadIdx.x & 15;
    int gid = blockIdx.x*16 + g;
    int d = gid & (DI-1), c = (gid >> 8) & (NCH-1), b = gid >> 12;
    float An = -__expf(A_log[d*DSt + n]);
    const float4 w0 = *reinterpret_cast<const float4*>(dtw + d*DTR);
    const float4 w1 = *reinterpret_cast<const float4*>(dtw + d*DTR + 4);
    const float bd = dtbias[d];
    int t0 = c*TC;
    const float* up  = xm  + (b*L2c + t0)*DI + d;
    const float* xrow = xdbl + (b*L2c + t0)*40;
    int srcbase = threadIdx.x & 0x30;   // group base lane within wave
    float P = 1.f, Q = 0.f;
    for (int jb=0; jb<TC; jb+=16){
        const float* xr = xrow + (jb+n)*40;
        float4 r0 = *reinterpret_cast<const float4*>(xr);
        float4 r1 = *reinterpret_cast<const float4*>(xr+4);
        float dtv = bd;
        dtv = fmaf(r0.x,w0.x, dtv); dtv = fmaf(r0.y,w0.y, dtv);
        dtv = fmaf(r0.z,w0.z, dtv); dtv = fmaf(r0.w,w0.w, dtv);
        dtv = fmaf(r1.x,w1.x, dtv); dtv = fmaf(r1.y,w1.y, dtv);
        dtv = fmaf(r1.z,w1.z, dtv); dtv = fmaf(r1.w,w1.w, dtv);
        dtv = softplusf_(dtv);
        #pragma unroll
        for (int jj=0; jj<16; ++jj){
            float dtj = __shfl(dtv, srcbase + jj);
            float u  = up[(jb+jj)*DI];
            float Bv = xrow[(jb+jj)*40 + DTR + n];
            float dA = __expf(dtj*An);
            P *= dA;
            Q = fmaf(dA, Q, dtj*u*Bv);
        }
    }
    Pb[gid*16+n] = P;
    Qb[gid*16+n] = Q;
}

// ---------------- pass 2 (stitch)
__global__ void k_scan2(const float* __restrict__ Pb, const float* __restrict__ Qb,
                        float* __restrict__ Hin)
{
    int i = blockIdx.x*256 + threadIdx.x;   // (b*DI+d)*16+n, 32768 total
    int dn = i & 4095, b = i >> 12;
    float hv = 0.f;
    #pragma unroll
    for (int c=0;c<NCH;++c){
        int off = (b*NCH+c)*4096 + dn;
        Hin[off] = hv;
        hv = fmaf(Pb[off], hv, Qb[off]);
    }
}

// ---------------- pass 3 with fused dt-projection + batched butterfly y-reduce
__global__ __launch_bounds__(256) void k_scan3(
    const float* __restrict__ xm, const float* __restrict__ xdbl,
    const float* __restrict__ xz,
    const float* __restrict__ dtw, const float* __restrict__ dtbias,
    const float* __restrict__ A_log, const float* __restrict__ Dp,
    const float* __restrict__ Hin, float* __restrict__ yb)
{
    int g = threadIdx.x >> 4, n = threadIdx.x & 15;
    int gid = blockIdx.x*16 + g;
    int d = gid & (DI-1), c = (gid >> 8) & (NCH-1), b = gid >> 12;
    float An = -__expf(A_log[d*DSt + n]);
    float Dv = Dp[d];
    const float4 w0 = *reinterpret_cast<const float4*>(dtw + d*DTR);
    const float4 w1 = *reinterpret_cast<const float4*>(dtw + d*DTR + 4);
    const float bd = dtbias[d];
    int t0 = c*TC;
    const float* up  = xm  + (b*L2c + t0)*DI + d;
    const float* zp  = xz  + (b*L2c + t0)*2*DI + DI + d;
    const float* xrow = xdbl + (b*L2c + t0)*40;
    float* yp = yb + (b*L2c + t0)*DI + d;
    int srcbase = threadIdx.x & 0x30;
    bool b8 = (n & 8), b4 = (n & 4), b2 = (n & 2), b1 = (n & 1);
    float hv = Hin[gid*16+n];
    for (int jb=0; jb<TC; jb+=16){
        const float* xr = xrow + (jb+n)*40;
        float4 r0 = *reinterpret_cast<const float4*>(xr);
        float4 r1 = *reinterpret_cast<const float4*>(xr+4);
        float dtv = bd;
        dtv = fmaf(r0.x,w0.x, dtv); dtv = fmaf(r0.y,w0.y, dtv);
        dtv = fmaf(r0.z,w0.z, dtv); dtv = fmaf(r0.w,w0.w, dtv);
        dtv = fmaf(r1.x,w1.x, dtv); dtv = fmaf(r1.y,w1.y, dtv);
        dtv = fmaf(r1.z,w1.z, dtv); dtv = fmaf(r1.w,w1.w, dtv);
        dtv = softplusf_(dtv);
        float p[16];
        float u_mine = 0.f;
        #pragma unroll
        for (int jj=0; jj<16; ++jj){
            int j = jb + jj;
            float dtj = __shfl(dtv, srcbase + jj);
            float u  = up[j*DI];
            float Bv = xrow[j*40 + DTR + n];
            float Cv = xrow[j*40 + DTR + DSt + n];
            float dA = __expf(dtj*An);
            hv = fmaf(dA, hv, dtj*u*Bv);
            p[jj] = hv*Cv;
            if (n == jj) u_mine = u;
        }
        // recursive-halving butterfly: lane n ends with y for step jb+n
        float s8[8];
        #pragma unroll
        for (int j=0;j<8;++j){
            float keep = b8 ? p[j+8] : p[j];
            float send = b8 ? p[j]   : p[j+8];
            s8[j] = keep + __shfl_xor(send, 8);
        }
        float s4[4];
        #pragma unroll
        for (int j=0;j<4;++j){
            float keep = b4 ? s8[j+4] : s8[j];
            float send = b4 ? s8[j]   : s8[j+4];
            s4[j] = keep + __shfl_xor(send, 4);
        }
        float s2[2];
        #pragma unroll
        for (int j=0;j<2;++j){
            float keep = b2 ? s4[j+2] : s4[j];
            float send = b2 ? s4[j]   : s4[j+2];
            s2[j] = keep + __shfl_xor(send, 2);
        }
        float keep = b1 ? s2[1] : s2[0];
        float send = b1 ? s2[0] : s2[1];
        float y = keep + __shfl_xor(send, 1);
        float zv = zp[(jb+n)*2*DI];
        yp[(jb+n)*DI] = (y + u_mine*Dv) * siluf_(zv);
    }
}

// ---------------- pool pass 1: partial mean over 64-token chunks
__global__ void k_pool1(const float* __restrict__ ln, float* __restrict__ partial)
{
    __shared__ float sbuf[256];
    int ch = blockIdx.x, b = blockIdx.y;
    int c = threadIdx.x & 127, half = threadIdx.x >> 7;
    int t0 = ch*(L2c/PCH);
    float s = 0.f;
    for (int j = half; j < L2c/PCH; j += 2)
        s += ln[(b*L2c + t0 + j)*DM + c];
    sbuf[threadIdx.x] = s;
    __syncthreads();
    if (half == 0)
        partial[(b*PCH + ch)*DM + c] = s + sbuf[threadIdx.x + 128];
}

// ---------------- pool pass 2
__global__ void k_pool2(const float* __restrict__ partial, float* __restrict__ pooled)
{
    int i = blockIdx.x*256 + threadIdx.x;   // b*128+c, 1024 total
    if (i >= Bc*DM) return;
    int b = i >> 7, c = i & 127;
    float s = 0.f;
    #pragma unroll
    for (int ch=0; ch<PCH; ++ch)
        s += partial[(b*PCH + ch)*DM + c];
    pooled[i] = s * (1.f/(float)L2c);
}

// ---------------- classifier
__global__ void k_cls(const float* __restrict__ pooled, const float* __restrict__ w,
                      const float* __restrict__ bias, float* __restrict__ out)
{
    int o = blockIdx.x*256 + threadIdx.x;
    if (o >= Bc*NC) return;
    int b = o/NC, n = o - b*NC;
    float s = bias[n];
    const float* pp = pooled + b*DM;
    const float* wp = w + n*DM;
    #pragma unroll 4
    for (int k=0;k<DM;++k) s = fmaf(pp[k], wp[k], s);
    out[o] = s;
}

extern "C" void kernel_launch(void* const* d_in, const int* in_sizes, int n_in,
                              void* d_out, int out_size, void* d_ws, size_t ws_size,
                              hipStream_t stream)
{
    const float* x        = (const float*)d_in[0];
    const float* conv0_w  = (const float*)d_in[1];
    const float* conv0_b  = (const float*)d_in[2];
    const float* bn0_g    = (const float*)d_in[3];
    const float* bn0_b    = (const float*)d_in[4];
    const float* conv1_w  = (const float*)d_in[5];
    const float* conv1_b  = (const float*)d_in[6];
    const float* bn1_g    = (const float*)d_in[7];
    const float* bn1_b    = (const float*)d_in[8];
    const float* ln_g     = (const float*)d_in[9];
    const float* ln_b     = (const float*)d_in[10];
    const float* in_proj_w= (const float*)d_in[11];
    const float* mconv_w  = (const float*)d_in[12];
    const float* mconv_b  = (const float*)d_in[13];
    const float* xproj_w  = (const float*)d_in[14];
    const float* dtproj_w = (const float*)d_in[15];
    const float* dtproj_b = (const float*)d_in[16];
    const float* A_log    = (const float*)d_in[17];
    const float* D_skip   = (const float*)d_in[18];
    const float* outproj_w= (const float*)d_in[19];
    const float* fnorm_g  = (const float*)d_in[20];
    const float* fnorm_b  = (const float*)d_in[21];
    const float* cls_w    = (const float*)d_in[22];
    const float* cls_b    = (const float*)d_in[23];
    float* out = (float*)d_out;

    float* ws = (float*)d_ws;
    float* sc0 = ws;        float* sh0 = ws+128;
    float* sc1 = ws+256;    float* sh1 = ws+384;
    float* h    = ws + 1024;              // 2,097,152
    float* ln   = h   + 2097152;          // 2,097,152
    float* xz   = ln  + 2097152;          // 8,388,608   (y0 aliases here)
    float* y0   = xz;
    float* xmc  = xz  + 8388608;          // 4,194,304   (y1 aliases here)
    float* y1   = xmc;
    float* xdbl = xmc + 4194304;          // 655,360
    float* wt   = xdbl + 655360;          // 147,456 (in old dtb hole)
    float* yb   = xdbl + 655360 + 4194304;
    float* pooled = yb + 4194304;         // 1,024
    float* partial = pooled + 1024;       // 4,096
    float* bns_s  = partial + 4096;       // 2,048
    float* bns_q  = bns_s + 2048;         // 2,048

    // scan P/Q/Hin scratch aliases the ln buffer (dead during scan phase)
    float* Pb  = ln;
    float* Qb  = ln + 524288;
    float* Hin = ln + 1048576;

    // conv stage
    k_wt<<<576, 256, 0, stream>>>(conv1_w, wt);
    k_conv0<<<16384, 256, 0, stream>>>(x, conv0_w, conv0_b, y0);
    k_bns1<<<dim3(16, DM), 256, 0, stream>>>(y0, L1, bns_s, bns_q);
    k_bns2<<<1, 128, 0, stream>>>(bns_s, bns_q, L1, bn0_g, bn0_b, sc0, sh0);
    k_conv1<<<dim3(L2c/32, Bc), 256, 0, stream>>>(y0, wt, conv1_b, sc0, sh0, y1);
    k_bns1<<<dim3(16, DM), 256, 0, stream>>>(y1, L2c, bns_s, bns_q);
    k_bns2<<<1, 128, 0, stream>>>(bns_s, bns_q, L2c, bn1_g, bn1_b, sc1, sh1);
    k_bnt<<<dim3(4, 64, Bc), 256, 0, stream>>>(y1, sc1, sh1, h);

    for (int i=0;i<NL;++i){
        k_ln<<<4096, 256, 0, stream>>>(h, ln_g + i*DM, ln_b + i*DM, ln);
        k_gemm<false><<<dim3(128, 8), 256, 0, stream>>>(
            ln, DM, in_proj_w + i*512*DM, DM, xz, 512, 16384, 512, DM);
        k_dwconv<<<16384, 256, 0, stream>>>(xz, mconv_w + i*DI*4, mconv_b + i*DI, xmc);
        k_gemm<false><<<dim3(128, 1), 256, 0, stream>>>(
            xmc, DI, xproj_w + i*40*DI, DI, xdbl, 40, 16384, 40, DI);
        k_scan1<<<2048, 256, 0, stream>>>(xmc, xdbl,
            dtproj_w + i*DI*DTR, dtproj_b + i*DI, A_log + i*DI*DSt, Pb, Qb);
        k_scan2<<<128, 256, 0, stream>>>(Pb, Qb, Hin);
        k_scan3<<<2048, 256, 0, stream>>>(xmc, xdbl, xz,
            dtproj_w + i*DI*DTR, dtproj_b + i*DI,
            A_log + i*DI*DSt, D_skip + i*DI, Hin, yb);
        k_gemm<true><<<dim3(128, 2), 256, 0, stream>>>(
            yb, DI, outproj_w + i*DM*DI, DI, h, DM, 16384, DM, DI);
    }

    k_ln<<<4096, 256, 0, stream>>>(h, fnorm_g, fnorm_b, ln);
    k_pool1<<<dim3(PCH, Bc), 256, 0, stream>>>(ln, partial);
    k_pool2<<<4, 256, 0, stream>>>(partial, pooled);
    k_cls<<<4, 256, 0, stream>>>(pooled, cls_w, cls_b, out);
}